// Round 9
// baseline (278.254 us; speedup 1.0000x reference)
//
#include <hip/hip_runtime.h>
#include <math.h>

typedef float f32x16 __attribute__((ext_vector_type(16)));
typedef short bf16x8 __attribute__((ext_vector_type(8)));
typedef short bf16x4 __attribute__((ext_vector_type(4)));
typedef unsigned short u16;
typedef unsigned int u32;

#define MFMA32(a, b, c) __builtin_amdgcn_mfma_f32_32x32x16_bf16(a, b, c, 0, 0, 0)

__device__ __forceinline__ u16 f2bf(float x) {
    u32 u = __float_as_uint(x);
    u += 0x7FFFu + ((u >> 16) & 1u);
    return (u16)(u >> 16);
}
__device__ __forceinline__ float bf2f(u16 h) {
    return __uint_as_float(((u32)h) << 16);
}

// ---------------------------------------------------------------------------
// prep v7b (unchanged): split bf16 hi/lo planes, V hi-only.
// ---------------------------------------------------------------------------
__global__ __launch_bounds__(256) void prep_kernel(
    const float* __restrict__ vectors, const float* __restrict__ scalars,
    const float* __restrict__ Wq, const float* __restrict__ Wq_s, const float* __restrict__ bq_s,
    const float* __restrict__ Wk, const float* __restrict__ Wk_s, const float* __restrict__ bk_s,
    const float* __restrict__ Wv,
    u16* __restrict__ qh, u16* __restrict__ ql,
    u16* __restrict__ kh, u16* __restrict__ kl,
    u16* __restrict__ vth)
{
    __shared__ float vl[64 * 68];
    __shared__ u16 vst[64 * 66];
    __shared__ float wls[1024];

    const int t = threadIdx.x;
    const int lane = t & 63;
    const int w = t >> 6;
    const int b = blockIdx.x >> 4;
    const int n0 = (blockIdx.x & 15) << 6;
    const long tok0 = (long)b * 1024 + n0;
    const float SC = 0.07216878364870323f;   // 1/sqrt(192)

    const float4* vin = (const float4*)(vectors + tok0 * 64);
#pragma unroll
    for (int r = 0; r < 4; ++r) {
        int i4 = t + (r << 8);
        int tok = i4 >> 4, c4 = (i4 & 15) << 2;
        *(float4*)&vl[tok * 68 + c4] = vin[i4];
    }
    for (int i = t; i < 1024; i += 256) wls[i] = (i < 512) ? Wq[i] : Wk[i - 512];
    __syncthreads();

#pragma unroll
    for (int r = 0; r < 4; ++r) {
        int gi = t + (r << 8);
        float* p = &vl[(gi >> 4) * 68 + ((gi & 15) << 2)];
        float x0 = p[0], x1 = p[1], x2 = p[2], x3 = p[3];
        float nrm = x0 * x0 - x1 * x1 - x2 * x2 - x3 * x3;
        float inv = 1.0f / sqrtf(fmaxf(fabsf(nrm), 1e-5f));
        p[0] = x0 * inv; p[1] = x1 * inv; p[2] = x2 * inv; p[3] = x3 * inv;
    }
    __syncthreads();

    if (w == 0) {
        float wrv[16];
#pragma unroll
        for (int j = 0; j < 16; ++j) wrv[j] = expf(Wv[(lane >> 2) * 16 + j]);
        const int vc = lane & 3;
        for (int tok = 0; tok < 64; ++tok) {
            float q = vl[tok * 68 + lane] * SC;
            u16 h = f2bf(q);
            long o_ = (tok0 + tok) * 128 + lane;
            qh[o_] = h; ql[o_] = f2bf(q - bf2f(h));
            const float* p0 = &vl[tok * 68 + vc];
            float a0 = 0.f, a1 = 0.f, a2 = 0.f, a3 = 0.f;
#pragma unroll
            for (int j = 0; j < 16; j += 4) {
                a0 = fmaf(wrv[j],     p0[j * 4],       a0);
                a1 = fmaf(wrv[j + 1], p0[(j + 1) * 4], a1);
                a2 = fmaf(wrv[j + 2], p0[(j + 2) * 4], a2);
                a3 = fmaf(wrv[j + 3], p0[(j + 3) * 4], a3);
            }
            vst[lane * 66 + tok] = f2bf((a0 + a1) + (a2 + a3));
        }
    } else if (w == 1) {
        const int i_ = lane >> 2, c = lane & 3;
        const float mc = (c == 0) ? 1.f : -1.f;
        float wqc[32];
#pragma unroll
        for (int f = 0; f < 32; ++f) wqc[f] = wls[f * 16 + i_];
        float gr[16];
#pragma unroll
        for (int jp = 0; jp < 16; ++jp) {
            float a0 = 0.f, a1 = 0.f;
#pragma unroll
            for (int f = 0; f < 32; f += 2) {
                a0 = fmaf(wqc[f],     wls[512 + f * 16 + jp],       a0);
                a1 = fmaf(wqc[f + 1], wls[512 + (f + 1) * 16 + jp], a1);
            }
            gr[jp] = (a0 + a1) * mc;
        }
        for (int tok = 0; tok < 64; ++tok) {
            const float* p0 = &vl[tok * 68 + c];
            float a0 = 0.f, a1 = 0.f, a2 = 0.f, a3 = 0.f;
#pragma unroll
            for (int jp = 0; jp < 16; jp += 4) {
                a0 = fmaf(gr[jp],     p0[jp * 4],       a0);
                a1 = fmaf(gr[jp + 1], p0[(jp + 1) * 4], a1);
                a2 = fmaf(gr[jp + 2], p0[(jp + 2) * 4], a2);
                a3 = fmaf(gr[jp + 3], p0[(jp + 3) * 4], a3);
            }
            float a = (a0 + a1) + (a2 + a3);
            u16 h = f2bf(a);
            long o_ = (tok0 + tok) * 128 + lane;
            kh[o_] = h; kl[o_] = f2bf(a - bf2f(h));
        }
    } else {
        const int tokbase = (w == 2) ? 0 : 32;
        const int l31 = lane & 31, g = lane >> 5;

        bf16x8 Ah[4], Al[4];
        const float* xrow = scalars + (tok0 + tokbase + l31) * 64 + g * 8;
#pragma unroll
        for (int kk = 0; kk < 4; ++kk) {
            float4 x0 = *(const float4*)(xrow + kk * 16);
            float4 x1 = *(const float4*)(xrow + kk * 16 + 4);
            float xs[8] = {x0.x, x0.y, x0.z, x0.w, x1.x, x1.y, x1.z, x1.w};
#pragma unroll
            for (int e = 0; e < 8; ++e) {
                u16 h = f2bf(xs[e]);
                Ah[kk][e] = (short)h;
                Al[kk][e] = (short)f2bf(xs[e] - bf2f(h));
            }
        }

#pragma unroll
        for (int ft = 0; ft < 4; ++ft) {
            const int isq = (ft < 2);
            const int fs = ((ft & 1) << 5) + l31;
            const float* wrow = (isq ? Wq_s : Wk_s) + fs * 64 + g * 8;
            f32x16 acc;
#pragma unroll
            for (int r = 0; r < 16; ++r) acc[r] = 0.f;
#pragma unroll
            for (int kk = 0; kk < 4; ++kk) {
                float4 w0_ = *(const float4*)(wrow + kk * 16);
                float4 w1_ = *(const float4*)(wrow + kk * 16 + 4);
                float ws_[8] = {w0_.x, w0_.y, w0_.z, w0_.w, w1_.x, w1_.y, w1_.z, w1_.w};
                bf16x8 Bh, Bl;
#pragma unroll
                for (int e = 0; e < 8; ++e) {
                    u16 h = f2bf(ws_[e]);
                    Bh[e] = (short)h;
                    Bl[e] = (short)f2bf(ws_[e] - bf2f(h));
                }
                acc = MFMA32(Ah[kk], Bh, acc);
                acc = MFMA32(Ah[kk], Bl, acc);
                acc = MFMA32(Al[kk], Bh, acc);
            }
            const float bias = (isq ? bq_s : bk_s)[fs];
            const float sc = isq ? SC : 1.f;
            u16* oh = isq ? qh : kh;
            u16* ol = isq ? ql : kl;
#pragma unroll
            for (int reg = 0; reg < 16; ++reg) {
                int trow = (reg & 3) + 8 * (reg >> 2) + 4 * g;
                float val = (acc[reg] + bias) * sc;
                u16 h = f2bf(val);
                long o_ = (tok0 + tokbase + trow) * 128 + 64 + fs;
                oh[o_] = h; ol[o_] = f2bf(val - bf2f(h));
            }
        }
    }
    __syncthreads();

#pragma unroll
    for (int r = 0; r < 8; ++r) {
        int i = t + (r << 8);
        int dv = i >> 5;
        int tp = (i & 31) << 1;
        u16 p0 = vst[dv * 66 + tp];
        u16 p1 = vst[dv * 66 + tp + 1];
        long o = ((long)b * 64 + dv) * 1024 + n0 + tp;
        *(u32*)(vth + o) = (u32)p0 | ((u32)p1 << 16);
    }
}

// ---------------------------------------------------------------------------
// attn v9: KV-split-2 (1024 blocks, 2 waves x 64 q, 512 keys/block).
// KH/KL double-buffered + V single-buffered (pitch 44, b64 writes) = 37.6 KB
// -> 4 blocks/CU = 2 waves/SIMD. Writes unnormalized partials (o, m, l).
// ---------------------------------------------------------------------------
__global__ __launch_bounds__(128, 2) void attn_kernel(
    const u16* __restrict__ qh, const u16* __restrict__ ql,
    const u16* __restrict__ kh, const u16* __restrict__ kl,
    const u16* __restrict__ vth, float* __restrict__ po,
    float2* __restrict__ pml)
{
    __shared__ u16 KH[2 * 32 * 128];
    __shared__ u16 KL[2 * 32 * 128];
    __shared__ u16 VH[64 * 44];

    const int t = threadIdx.x;
    const int lane = t & 63;
    const int w = t >> 6;            // 0..1
    const int l31 = lane & 31, g = lane >> 5;

    const int bid = blockIdx.x;      // 0..1023
    const int xcd = bid & 7;
    const int idx = bid >> 3;        // 0..127
    const int b = xcd * 8 + (idx >> 4);
    const int qt = (idx >> 1) & 7;
    const int half = idx & 1;
    const int kv0 = half << 9;

    const int qiA = qt * 128 + w * 64 + l31;
    const long qtokA = (long)b * 1024 + qiA;
    const long qtokB = qtokA + 32;

    // ---- Q fragments, 2 sets ----
    bf16x8 QhA[8], QlA[8], QhB[8], QlB[8];
    {
        const u16* pah = qh + qtokA * 128 + g * 8;
        const u16* pal = ql + qtokA * 128 + g * 8;
        const u16* pbh = qh + qtokB * 128 + g * 8;
        const u16* pbl = ql + qtokB * 128 + g * 8;
#pragma unroll
        for (int c = 0; c < 8; ++c) {
            QhA[c] = *(const bf16x8*)(pah + c * 16);
            QlA[c] = *(const bf16x8*)(pal + c * 16);
            QhB[c] = *(const bf16x8*)(pbh + c * 16);
            QlB[c] = *(const bf16x8*)(pbl + c * 16);
        }
    }

    // ---- staging maps ----
    const int srow = t >> 2, sq4 = t & 3;
    const u16* khg = kh + ((long)b * 1024 + kv0 + srow) * 128 + sq4 * 32;
    const u16* klg = kl + ((long)b * 1024 + kv0 + srow) * 128 + sq4 * 32;
    const int sdv = t >> 1, shalf = t & 1;
    const u16* vhg = vth + ((long)b * 64 + sdv) * 1024 + kv0 + shalf * 16;

    const int kdst0 = srow * 128 + (((sq4 << 2) + 0) ^ (srow & 15)) * 8;
    const int kdst1 = srow * 128 + (((sq4 << 2) + 1) ^ (srow & 15)) * 8;
    const int kdst2 = srow * 128 + (((sq4 << 2) + 2) ^ (srow & 15)) * 8;
    const int kdst3 = srow * 128 + (((sq4 << 2) + 3) ^ (srow & 15)) * 8;
    u16* vdst = VH + sdv * 44 + shalf * 16;

    int4 rk0, rk1, rk2, rk3, rl0, rl1, rl2, rl3, rv0, rv1;

#define LOADT(ktl) do { \
        const u16* p1 = khg + (long)(ktl) * 128; \
        rk0 = *(const int4*)(p1);      rk1 = *(const int4*)(p1 + 8); \
        rk2 = *(const int4*)(p1 + 16); rk3 = *(const int4*)(p1 + 24); \
        const u16* p2 = klg + (long)(ktl) * 128; \
        rl0 = *(const int4*)(p2);      rl1 = *(const int4*)(p2 + 8); \
        rl2 = *(const int4*)(p2 + 16); rl3 = *(const int4*)(p2 + 24); \
        rv0 = *(const int4*)(vhg + (ktl)); \
        rv1 = *(const int4*)(vhg + (ktl) + 8); \
    } while (0)

#define WRITET(buf) do { \
        u16* d1 = KH + (buf) * 4096; \
        *(int4*)(d1 + kdst0) = rk0; *(int4*)(d1 + kdst1) = rk1; \
        *(int4*)(d1 + kdst2) = rk2; *(int4*)(d1 + kdst3) = rk3; \
        u16* d2 = KL + (buf) * 4096; \
        *(int4*)(d2 + kdst0) = rl0; *(int4*)(d2 + kdst1) = rl1; \
        *(int4*)(d2 + kdst2) = rl2; *(int4*)(d2 + kdst3) = rl3; \
        *(int2*)(vdst)      = make_int2(rv0.x, rv0.y); \
        *(int2*)(vdst + 4)  = make_int2(rv0.z, rv0.w); \
        *(int2*)(vdst + 8)  = make_int2(rv1.x, rv1.y); \
        *(int2*)(vdst + 12) = make_int2(rv1.z, rv1.w); \
    } while (0)

    f32x16 oA0, oA1, oB0, oB1;
#pragma unroll
    for (int r = 0; r < 16; ++r) { oA0[r] = 0.f; oA1[r] = 0.f; oB0[r] = 0.f; oB1[r] = 0.f; }
    float mA = -1e30f, lA = 0.f, mB = -1e30f, lB = 0.f;

    LOADT(0);
    WRITET(0);
    __syncthreads();

    for (int it = 0; it < 16; ++it) {
        const int cb = it & 1;
        if (it < 15) LOADT((it + 1) * 32);

        // ---- QK^T ----
        f32x16 sA0, sB0, sA1, sB1;
#pragma unroll
        for (int r = 0; r < 16; ++r) { sA0[r] = 0.f; sB0[r] = 0.f; sA1[r] = 0.f; sB1[r] = 0.f; }
        const u16* kbh = KH + cb * 4096 + l31 * 128;
        const u16* kbl = KL + cb * 4096 + l31 * 128;
        const int rs = l31 & 15;
        __builtin_amdgcn_s_setprio(1);
#pragma unroll
        for (int c = 0; c < 8; ++c) {
            const int off = ((g + 2 * c) ^ rs) * 8;
            bf16x8 fh = *(const bf16x8*)(kbh + off);
            bf16x8 fl = *(const bf16x8*)(kbl + off);
            sA0 = MFMA32(fh, QhA[c], sA0);
            sA1 = MFMA32(fh, QhB[c], sA1);
            sB0 = MFMA32(fh, QlA[c], sB0);
            sB1 = MFMA32(fh, QlB[c], sB1);
            sB0 = MFMA32(fl, QhA[c], sB0);
            sB1 = MFMA32(fl, QhB[c], sB1);
        }
        __builtin_amdgcn_s_setprio(0);

        // ---- softmax A ----
        bf16x8 phA0, phA1, phB0, phB1;
        {
            float s0[16];
#pragma unroll
            for (int r = 0; r < 16; ++r) s0[r] = sA0[r] + sB0[r];
            float mt = s0[0];
#pragma unroll
            for (int r = 1; r < 16; ++r) mt = fmaxf(mt, s0[r]);
            mt = fmaxf(mt, __shfl_xor(mt, 32));
            if (!__all(mt - mA <= 8.f)) {
                float mn = fmaxf(mA, mt);
                float corr = __expf(mA - mn);
                lA *= corr;
#pragma unroll
                for (int r = 0; r < 16; ++r) { oA0[r] *= corr; oA1[r] *= corr; }
                mA = mn;
            }
            float ps = 0.f;
#pragma unroll
            for (int r = 0; r < 16; ++r) { s0[r] = __expf(s0[r] - mA); ps += s0[r]; }
            ps += __shfl_xor(ps, 32);
            lA += ps;
#pragma unroll
            for (int e = 0; e < 8; ++e) {
                phA0[e] = (short)f2bf(s0[e]);
                phA1[e] = (short)f2bf(s0[8 + e]);
            }
        }
        // ---- softmax B ----
        {
            float s1[16];
#pragma unroll
            for (int r = 0; r < 16; ++r) s1[r] = sA1[r] + sB1[r];
            float mt = s1[0];
#pragma unroll
            for (int r = 1; r < 16; ++r) mt = fmaxf(mt, s1[r]);
            mt = fmaxf(mt, __shfl_xor(mt, 32));
            if (!__all(mt - mB <= 8.f)) {
                float mn = fmaxf(mB, mt);
                float corr = __expf(mB - mn);
                lB *= corr;
#pragma unroll
                for (int r = 0; r < 16; ++r) { oB0[r] *= corr; oB1[r] *= corr; }
                mB = mn;
            }
            float ps = 0.f;
#pragma unroll
            for (int r = 0; r < 16; ++r) { s1[r] = __expf(s1[r] - mB); ps += s1[r]; }
            ps += __shfl_xor(ps, 32);
            lB += ps;
#pragma unroll
            for (int e = 0; e < 8; ++e) {
                phB0[e] = (short)f2bf(s1[e]);
                phB1[e] = (short)f2bf(s1[8 + e]);
            }
        }

        // ---- V fragments (single buffer, pitch 44) ----
        bf16x8 v00, v01, v10, v11;
        {
            const u16* p00 = VH + l31 * 44 + g * 4;
            const u16* p10 = VH + (32 + l31) * 44 + g * 4;
            bf16x4 a0 = *(const bf16x4*)(p00);      bf16x4 a1 = *(const bf16x4*)(p00 + 8);
            bf16x4 b0 = *(const bf16x4*)(p00 + 16); bf16x4 b1 = *(const bf16x4*)(p00 + 24);
            bf16x4 c0 = *(const bf16x4*)(p10);      bf16x4 c1 = *(const bf16x4*)(p10 + 8);
            bf16x4 d0 = *(const bf16x4*)(p10 + 16); bf16x4 d1 = *(const bf16x4*)(p10 + 24);
            v00 = __builtin_shufflevector(a0, a1, 0, 1, 2, 3, 4, 5, 6, 7);
            v01 = __builtin_shufflevector(b0, b1, 0, 1, 2, 3, 4, 5, 6, 7);
            v10 = __builtin_shufflevector(c0, c1, 0, 1, 2, 3, 4, 5, 6, 7);
            v11 = __builtin_shufflevector(d0, d1, 0, 1, 2, 3, 4, 5, 6, 7);
        }

        __builtin_amdgcn_s_setprio(1);
        oA0 = MFMA32(v00, phA0, oA0);
        oA0 = MFMA32(v01, phA1, oA0);
        oA1 = MFMA32(v10, phA0, oA1);
        oA1 = MFMA32(v11, phA1, oA1);
        oB0 = MFMA32(v00, phB0, oB0);
        oB0 = MFMA32(v01, phB1, oB0);
        oB1 = MFMA32(v10, phB0, oB1);
        oB1 = MFMA32(v11, phB1, oB1);
        __builtin_amdgcn_s_setprio(0);

        __syncthreads();                  // all PV reads of VH done
        if (it < 15) WRITET(cb ^ 1);
        __syncthreads();                  // staging visible
    }

    // ---- epilogue: unnormalized partials ----
    float* poA = po + (((long)half * 64 + b) * 1024 + qiA) * 64;
    float* poB = poA + 32 * 64;
#pragma unroll
    for (int sg = 0; sg < 4; ++sg) {
        *(float4*)(poA + sg * 8 + g * 4) = make_float4(oA0[4*sg+0], oA0[4*sg+1], oA0[4*sg+2], oA0[4*sg+3]);
        *(float4*)(poA + 32 + sg * 8 + g * 4) = make_float4(oA1[4*sg+0], oA1[4*sg+1], oA1[4*sg+2], oA1[4*sg+3]);
        *(float4*)(poB + sg * 8 + g * 4) = make_float4(oB0[4*sg+0], oB0[4*sg+1], oB0[4*sg+2], oB0[4*sg+3]);
        *(float4*)(poB + 32 + sg * 8 + g * 4) = make_float4(oB1[4*sg+0], oB1[4*sg+1], oB1[4*sg+2], oB1[4*sg+3]);
    }
    if (g == 0) {
        pml[((long)half * 64 + b) * 1024 + qiA] = make_float2(mA, lA);
        pml[((long)half * 64 + b) * 1024 + qiA + 32] = make_float2(mB, lB);
    }
#undef LOADT
#undef WRITET
}

// ---------------------------------------------------------------------------
// merge: combine the two KV-halves' partials.
// ---------------------------------------------------------------------------
__global__ __launch_bounds__(256) void merge_kernel(
    const float* __restrict__ po, const float2* __restrict__ pml,
    float* __restrict__ out)
{
    const int idx = blockIdx.x * 256 + threadIdx.x;   // 0..262143
    const int q = idx >> 2;
    const int part = idx & 3;
    float2 a = pml[q];
    float2 c = pml[65536 + q];
    float m = fmaxf(a.x, c.x);
    float w0 = __expf(a.x - m), w1 = __expf(c.x - m);
    float inv = 1.0f / (w0 * a.y + w1 * c.y);
    const float4* o0 = (const float4*)(po + (long)q * 64 + part * 16);
    const float4* o1 = (const float4*)(po + 4194304 + (long)q * 64 + part * 16);
    float4* op = (float4*)(out + (long)q * 64 + part * 16);
#pragma unroll
    for (int j = 0; j < 4; ++j) {
        float4 x = o0[j], y = o1[j];
        op[j] = make_float4((w0 * x.x + w1 * y.x) * inv,
                            (w0 * x.y + w1 * y.y) * inv,
                            (w0 * x.z + w1 * y.z) * inv,
                            (w0 * x.w + w1 * y.w) * inv);
    }
}

extern "C" void kernel_launch(void* const* d_in, const int* in_sizes, int n_in,
                              void* d_out, int out_size, void* d_ws, size_t ws_size,
                              hipStream_t stream) {
    const float* vectors = (const float*)d_in[0];
    const float* scalars = (const float*)d_in[1];
    const float* Wq   = (const float*)d_in[2];
    const float* Wq_s = (const float*)d_in[3];
    const float* bq_s = (const float*)d_in[4];
    const float* Wk   = (const float*)d_in[5];
    const float* Wk_s = (const float*)d_in[6];
    const float* bk_s = (const float*)d_in[7];
    const float* Wv   = (const float*)d_in[8];
    float* o = (float*)d_out;

    u16* qh  = (u16*)d_ws;                 // 16MB each
    u16* ql  = qh + 8388608;
    u16* kh  = ql + 8388608;
    u16* kl  = kh + 8388608;
    u16* vth = kl + 8388608;               // 8MB
    float* po = (float*)(vth + 4194304);   // 2*65536*64 f32 = 33.5MB
    float2* pml = (float2*)(po + 8388608); // 1MB

    prep_kernel<<<1024, 256, 0, stream>>>(vectors, scalars, Wq, Wq_s, bq_s,
                                          Wk, Wk_s, bk_s, Wv,
                                          qh, ql, kh, kl, vth);
    attn_kernel<<<1024, 128, 0, stream>>>(qh, ql, kh, kl, vth, po, pml);
    merge_kernel<<<1024, 256, 0, stream>>>(po, pml, o);
}

// Round 10
// 165.257 us; speedup vs baseline: 1.6838x; 1.6838x over previous
//
#include <hip/hip_runtime.h>
#include <math.h>

typedef float f32x16 __attribute__((ext_vector_type(16)));
typedef short bf16x8 __attribute__((ext_vector_type(8)));
typedef short bf16x4 __attribute__((ext_vector_type(4)));
typedef unsigned short u16;
typedef unsigned int u32;

#define MFMA32(a, b, c) __builtin_amdgcn_mfma_f32_32x32x16_bf16(a, b, c, 0, 0, 0)

__device__ __forceinline__ u16 f2bf(float x) {
    u32 u = __float_as_uint(x);
    u += 0x7FFFu + ((u >> 16) & 1u);
    return (u16)(u >> 16);
}
__device__ __forceinline__ float bf2f(u16 h) {
    return __uint_as_float(((u32)h) << 16);
}

// ---------------------------------------------------------------------------
// prep v7b (unchanged): split bf16 hi/lo planes, V hi-only.
// ---------------------------------------------------------------------------
__global__ __launch_bounds__(256) void prep_kernel(
    const float* __restrict__ vectors, const float* __restrict__ scalars,
    const float* __restrict__ Wq, const float* __restrict__ Wq_s, const float* __restrict__ bq_s,
    const float* __restrict__ Wk, const float* __restrict__ Wk_s, const float* __restrict__ bk_s,
    const float* __restrict__ Wv,
    u16* __restrict__ qh, u16* __restrict__ ql,
    u16* __restrict__ kh, u16* __restrict__ kl,
    u16* __restrict__ vth)
{
    __shared__ float vl[64 * 68];
    __shared__ u16 vst[64 * 66];
    __shared__ float wls[1024];

    const int t = threadIdx.x;
    const int lane = t & 63;
    const int w = t >> 6;
    const int b = blockIdx.x >> 4;
    const int n0 = (blockIdx.x & 15) << 6;
    const long tok0 = (long)b * 1024 + n0;
    const float SC = 0.07216878364870323f;   // 1/sqrt(192)

    const float4* vin = (const float4*)(vectors + tok0 * 64);
#pragma unroll
    for (int r = 0; r < 4; ++r) {
        int i4 = t + (r << 8);
        int tok = i4 >> 4, c4 = (i4 & 15) << 2;
        *(float4*)&vl[tok * 68 + c4] = vin[i4];
    }
    for (int i = t; i < 1024; i += 256) wls[i] = (i < 512) ? Wq[i] : Wk[i - 512];
    __syncthreads();

#pragma unroll
    for (int r = 0; r < 4; ++r) {
        int gi = t + (r << 8);
        float* p = &vl[(gi >> 4) * 68 + ((gi & 15) << 2)];
        float x0 = p[0], x1 = p[1], x2 = p[2], x3 = p[3];
        float nrm = x0 * x0 - x1 * x1 - x2 * x2 - x3 * x3;
        float inv = 1.0f / sqrtf(fmaxf(fabsf(nrm), 1e-5f));
        p[0] = x0 * inv; p[1] = x1 * inv; p[2] = x2 * inv; p[3] = x3 * inv;
    }
    __syncthreads();

    if (w == 0) {
        float wrv[16];
#pragma unroll
        for (int j = 0; j < 16; ++j) wrv[j] = expf(Wv[(lane >> 2) * 16 + j]);
        const int vc = lane & 3;
        for (int tok = 0; tok < 64; ++tok) {
            float q = vl[tok * 68 + lane] * SC;
            u16 h = f2bf(q);
            long o_ = (tok0 + tok) * 128 + lane;
            qh[o_] = h; ql[o_] = f2bf(q - bf2f(h));
            const float* p0 = &vl[tok * 68 + vc];
            float a0 = 0.f, a1 = 0.f, a2 = 0.f, a3 = 0.f;
#pragma unroll
            for (int j = 0; j < 16; j += 4) {
                a0 = fmaf(wrv[j],     p0[j * 4],       a0);
                a1 = fmaf(wrv[j + 1], p0[(j + 1) * 4], a1);
                a2 = fmaf(wrv[j + 2], p0[(j + 2) * 4], a2);
                a3 = fmaf(wrv[j + 3], p0[(j + 3) * 4], a3);
            }
            vst[lane * 66 + tok] = f2bf((a0 + a1) + (a2 + a3));
        }
    } else if (w == 1) {
        const int i_ = lane >> 2, c = lane & 3;
        const float mc = (c == 0) ? 1.f : -1.f;
        float wqc[32];
#pragma unroll
        for (int f = 0; f < 32; ++f) wqc[f] = wls[f * 16 + i_];
        float gr[16];
#pragma unroll
        for (int jp = 0; jp < 16; ++jp) {
            float a0 = 0.f, a1 = 0.f;
#pragma unroll
            for (int f = 0; f < 32; f += 2) {
                a0 = fmaf(wqc[f],     wls[512 + f * 16 + jp],       a0);
                a1 = fmaf(wqc[f + 1], wls[512 + (f + 1) * 16 + jp], a1);
            }
            gr[jp] = (a0 + a1) * mc;
        }
        for (int tok = 0; tok < 64; ++tok) {
            const float* p0 = &vl[tok * 68 + c];
            float a0 = 0.f, a1 = 0.f, a2 = 0.f, a3 = 0.f;
#pragma unroll
            for (int jp = 0; jp < 16; jp += 4) {
                a0 = fmaf(gr[jp],     p0[jp * 4],       a0);
                a1 = fmaf(gr[jp + 1], p0[(jp + 1) * 4], a1);
                a2 = fmaf(gr[jp + 2], p0[(jp + 2) * 4], a2);
                a3 = fmaf(gr[jp + 3], p0[(jp + 3) * 4], a3);
            }
            float a = (a0 + a1) + (a2 + a3);
            u16 h = f2bf(a);
            long o_ = (tok0 + tok) * 128 + lane;
            kh[o_] = h; kl[o_] = f2bf(a - bf2f(h));
        }
    } else {
        const int tokbase = (w == 2) ? 0 : 32;
        const int l31 = lane & 31, g = lane >> 5;

        bf16x8 Ah[4], Al[4];
        const float* xrow = scalars + (tok0 + tokbase + l31) * 64 + g * 8;
#pragma unroll
        for (int kk = 0; kk < 4; ++kk) {
            float4 x0 = *(const float4*)(xrow + kk * 16);
            float4 x1 = *(const float4*)(xrow + kk * 16 + 4);
            float xs[8] = {x0.x, x0.y, x0.z, x0.w, x1.x, x1.y, x1.z, x1.w};
#pragma unroll
            for (int e = 0; e < 8; ++e) {
                u16 h = f2bf(xs[e]);
                Ah[kk][e] = (short)h;
                Al[kk][e] = (short)f2bf(xs[e] - bf2f(h));
            }
        }

#pragma unroll
        for (int ft = 0; ft < 4; ++ft) {
            const int isq = (ft < 2);
            const int fs = ((ft & 1) << 5) + l31;
            const float* wrow = (isq ? Wq_s : Wk_s) + fs * 64 + g * 8;
            f32x16 acc;
#pragma unroll
            for (int r = 0; r < 16; ++r) acc[r] = 0.f;
#pragma unroll
            for (int kk = 0; kk < 4; ++kk) {
                float4 w0_ = *(const float4*)(wrow + kk * 16);
                float4 w1_ = *(const float4*)(wrow + kk * 16 + 4);
                float ws_[8] = {w0_.x, w0_.y, w0_.z, w0_.w, w1_.x, w1_.y, w1_.z, w1_.w};
                bf16x8 Bh, Bl;
#pragma unroll
                for (int e = 0; e < 8; ++e) {
                    u16 h = f2bf(ws_[e]);
                    Bh[e] = (short)h;
                    Bl[e] = (short)f2bf(ws_[e] - bf2f(h));
                }
                acc = MFMA32(Ah[kk], Bh, acc);
                acc = MFMA32(Ah[kk], Bl, acc);
                acc = MFMA32(Al[kk], Bh, acc);
            }
            const float bias = (isq ? bq_s : bk_s)[fs];
            const float sc = isq ? SC : 1.f;
            u16* oh = isq ? qh : kh;
            u16* ol = isq ? ql : kl;
#pragma unroll
            for (int reg = 0; reg < 16; ++reg) {
                int trow = (reg & 3) + 8 * (reg >> 2) + 4 * g;
                float val = (acc[reg] + bias) * sc;
                u16 h = f2bf(val);
                long o_ = (tok0 + tokbase + trow) * 128 + 64 + fs;
                oh[o_] = h; ol[o_] = f2bf(val - bf2f(h));
            }
        }
    }
    __syncthreads();

#pragma unroll
    for (int r = 0; r < 8; ++r) {
        int i = t + (r << 8);
        int dv = i >> 5;
        int tp = (i & 31) << 1;
        u16 p0 = vst[dv * 66 + tp];
        u16 p1 = vst[dv * 66 + tp + 1];
        long o = ((long)b * 64 + dv) * 1024 + n0 + tp;
        *(u32*)(vth + o) = (u32)p0 | ((u32)p1 << 16);
    }
}

// ---------------------------------------------------------------------------
// attn v9b: KV-split-2 (1024 blocks, 2 waves x 64 q, 512 keys/block).
// launch_bounds(128) ONLY — no min-waves hint (the ",2" in v9 capped VGPRs
// at 128 and spilled; 228 VGPRs <= 256 already allows 2 waves/SIMD).
// ---------------------------------------------------------------------------
__global__ __launch_bounds__(128) void attn_kernel(
    const u16* __restrict__ qh, const u16* __restrict__ ql,
    const u16* __restrict__ kh, const u16* __restrict__ kl,
    const u16* __restrict__ vth, float* __restrict__ po,
    float2* __restrict__ pml)
{
    __shared__ u16 KH[2 * 32 * 128];
    __shared__ u16 KL[2 * 32 * 128];
    __shared__ u16 VH[64 * 44];

    const int t = threadIdx.x;
    const int lane = t & 63;
    const int w = t >> 6;            // 0..1
    const int l31 = lane & 31, g = lane >> 5;

    const int bid = blockIdx.x;      // 0..1023
    const int xcd = bid & 7;
    const int idx = bid >> 3;        // 0..127
    const int b = xcd * 8 + (idx >> 4);
    const int qt = (idx >> 1) & 7;
    const int half = idx & 1;
    const int kv0 = half << 9;

    const int qiA = qt * 128 + w * 64 + l31;
    const long qtokA = (long)b * 1024 + qiA;
    const long qtokB = qtokA + 32;

    // ---- Q fragments, 2 sets ----
    bf16x8 QhA[8], QlA[8], QhB[8], QlB[8];
    {
        const u16* pah = qh + qtokA * 128 + g * 8;
        const u16* pal = ql + qtokA * 128 + g * 8;
        const u16* pbh = qh + qtokB * 128 + g * 8;
        const u16* pbl = ql + qtokB * 128 + g * 8;
#pragma unroll
        for (int c = 0; c < 8; ++c) {
            QhA[c] = *(const bf16x8*)(pah + c * 16);
            QlA[c] = *(const bf16x8*)(pal + c * 16);
            QhB[c] = *(const bf16x8*)(pbh + c * 16);
            QlB[c] = *(const bf16x8*)(pbl + c * 16);
        }
    }

    // ---- staging maps ----
    const int srow = t >> 2, sq4 = t & 3;
    const u16* khg = kh + ((long)b * 1024 + kv0 + srow) * 128 + sq4 * 32;
    const u16* klg = kl + ((long)b * 1024 + kv0 + srow) * 128 + sq4 * 32;
    const int sdv = t >> 1, shalf = t & 1;
    const u16* vhg = vth + ((long)b * 64 + sdv) * 1024 + kv0 + shalf * 16;

    const int kdst0 = srow * 128 + (((sq4 << 2) + 0) ^ (srow & 15)) * 8;
    const int kdst1 = srow * 128 + (((sq4 << 2) + 1) ^ (srow & 15)) * 8;
    const int kdst2 = srow * 128 + (((sq4 << 2) + 2) ^ (srow & 15)) * 8;
    const int kdst3 = srow * 128 + (((sq4 << 2) + 3) ^ (srow & 15)) * 8;
    u16* vdst = VH + sdv * 44 + shalf * 16;

    int4 rk0, rk1, rk2, rk3, rl0, rl1, rl2, rl3, rv0, rv1;

#define LOADT(ktl) do { \
        const u16* p1 = khg + (long)(ktl) * 128; \
        rk0 = *(const int4*)(p1);      rk1 = *(const int4*)(p1 + 8); \
        rk2 = *(const int4*)(p1 + 16); rk3 = *(const int4*)(p1 + 24); \
        const u16* p2 = klg + (long)(ktl) * 128; \
        rl0 = *(const int4*)(p2);      rl1 = *(const int4*)(p2 + 8); \
        rl2 = *(const int4*)(p2 + 16); rl3 = *(const int4*)(p2 + 24); \
        rv0 = *(const int4*)(vhg + (ktl)); \
        rv1 = *(const int4*)(vhg + (ktl) + 8); \
    } while (0)

#define WRITET(buf) do { \
        u16* d1 = KH + (buf) * 4096; \
        *(int4*)(d1 + kdst0) = rk0; *(int4*)(d1 + kdst1) = rk1; \
        *(int4*)(d1 + kdst2) = rk2; *(int4*)(d1 + kdst3) = rk3; \
        u16* d2 = KL + (buf) * 4096; \
        *(int4*)(d2 + kdst0) = rl0; *(int4*)(d2 + kdst1) = rl1; \
        *(int4*)(d2 + kdst2) = rl2; *(int4*)(d2 + kdst3) = rl3; \
        *(int2*)(vdst)      = make_int2(rv0.x, rv0.y); \
        *(int2*)(vdst + 4)  = make_int2(rv0.z, rv0.w); \
        *(int2*)(vdst + 8)  = make_int2(rv1.x, rv1.y); \
        *(int2*)(vdst + 12) = make_int2(rv1.z, rv1.w); \
    } while (0)

    f32x16 oA0, oA1, oB0, oB1;
#pragma unroll
    for (int r = 0; r < 16; ++r) { oA0[r] = 0.f; oA1[r] = 0.f; oB0[r] = 0.f; oB1[r] = 0.f; }
    float mA = -1e30f, lA = 0.f, mB = -1e30f, lB = 0.f;

    LOADT(0);
    WRITET(0);
    __syncthreads();

    for (int it = 0; it < 16; ++it) {
        const int cb = it & 1;
        if (it < 15) LOADT((it + 1) * 32);

        // ---- QK^T ----
        f32x16 sA0, sB0, sA1, sB1;
#pragma unroll
        for (int r = 0; r < 16; ++r) { sA0[r] = 0.f; sB0[r] = 0.f; sA1[r] = 0.f; sB1[r] = 0.f; }
        const u16* kbh = KH + cb * 4096 + l31 * 128;
        const u16* kbl = KL + cb * 4096 + l31 * 128;
        const int rs = l31 & 15;
        __builtin_amdgcn_s_setprio(1);
#pragma unroll
        for (int c = 0; c < 8; ++c) {
            const int off = ((g + 2 * c) ^ rs) * 8;
            bf16x8 fh = *(const bf16x8*)(kbh + off);
            bf16x8 fl = *(const bf16x8*)(kbl + off);
            sA0 = MFMA32(fh, QhA[c], sA0);
            sA1 = MFMA32(fh, QhB[c], sA1);
            sB0 = MFMA32(fh, QlA[c], sB0);
            sB1 = MFMA32(fh, QlB[c], sB1);
            sB0 = MFMA32(fl, QhA[c], sB0);
            sB1 = MFMA32(fl, QhB[c], sB1);
        }
        __builtin_amdgcn_s_setprio(0);

        // ---- softmax A ----
        bf16x8 phA0, phA1, phB0, phB1;
        {
            float s0[16];
#pragma unroll
            for (int r = 0; r < 16; ++r) s0[r] = sA0[r] + sB0[r];
            float mt = s0[0];
#pragma unroll
            for (int r = 1; r < 16; ++r) mt = fmaxf(mt, s0[r]);
            mt = fmaxf(mt, __shfl_xor(mt, 32));
            if (!__all(mt - mA <= 8.f)) {
                float mn = fmaxf(mA, mt);
                float corr = __expf(mA - mn);
                lA *= corr;
#pragma unroll
                for (int r = 0; r < 16; ++r) { oA0[r] *= corr; oA1[r] *= corr; }
                mA = mn;
            }
            float ps = 0.f;
#pragma unroll
            for (int r = 0; r < 16; ++r) { s0[r] = __expf(s0[r] - mA); ps += s0[r]; }
            ps += __shfl_xor(ps, 32);
            lA += ps;
#pragma unroll
            for (int e = 0; e < 8; ++e) {
                phA0[e] = (short)f2bf(s0[e]);
                phA1[e] = (short)f2bf(s0[8 + e]);
            }
        }
        // ---- softmax B ----
        {
            float s1[16];
#pragma unroll
            for (int r = 0; r < 16; ++r) s1[r] = sA1[r] + sB1[r];
            float mt = s1[0];
#pragma unroll
            for (int r = 1; r < 16; ++r) mt = fmaxf(mt, s1[r]);
            mt = fmaxf(mt, __shfl_xor(mt, 32));
            if (!__all(mt - mB <= 8.f)) {
                float mn = fmaxf(mB, mt);
                float corr = __expf(mB - mn);
                lB *= corr;
#pragma unroll
                for (int r = 0; r < 16; ++r) { oB0[r] *= corr; oB1[r] *= corr; }
                mB = mn;
            }
            float ps = 0.f;
#pragma unroll
            for (int r = 0; r < 16; ++r) { s1[r] = __expf(s1[r] - mB); ps += s1[r]; }
            ps += __shfl_xor(ps, 32);
            lB += ps;
#pragma unroll
            for (int e = 0; e < 8; ++e) {
                phB0[e] = (short)f2bf(s1[e]);
                phB1[e] = (short)f2bf(s1[8 + e]);
            }
        }

        // ---- V fragments (single buffer, pitch 44) ----
        bf16x8 v00, v01, v10, v11;
        {
            const u16* p00 = VH + l31 * 44 + g * 4;
            const u16* p10 = VH + (32 + l31) * 44 + g * 4;
            bf16x4 a0 = *(const bf16x4*)(p00);      bf16x4 a1 = *(const bf16x4*)(p00 + 8);
            bf16x4 b0 = *(const bf16x4*)(p00 + 16); bf16x4 b1 = *(const bf16x4*)(p00 + 24);
            bf16x4 c0 = *(const bf16x4*)(p10);      bf16x4 c1 = *(const bf16x4*)(p10 + 8);
            bf16x4 d0 = *(const bf16x4*)(p10 + 16); bf16x4 d1 = *(const bf16x4*)(p10 + 24);
            v00 = __builtin_shufflevector(a0, a1, 0, 1, 2, 3, 4, 5, 6, 7);
            v01 = __builtin_shufflevector(b0, b1, 0, 1, 2, 3, 4, 5, 6, 7);
            v10 = __builtin_shufflevector(c0, c1, 0, 1, 2, 3, 4, 5, 6, 7);
            v11 = __builtin_shufflevector(d0, d1, 0, 1, 2, 3, 4, 5, 6, 7);
        }

        __builtin_amdgcn_s_setprio(1);
        oA0 = MFMA32(v00, phA0, oA0);
        oA0 = MFMA32(v01, phA1, oA0);
        oA1 = MFMA32(v10, phA0, oA1);
        oA1 = MFMA32(v11, phA1, oA1);
        oB0 = MFMA32(v00, phB0, oB0);
        oB0 = MFMA32(v01, phB1, oB0);
        oB1 = MFMA32(v10, phB0, oB1);
        oB1 = MFMA32(v11, phB1, oB1);
        __builtin_amdgcn_s_setprio(0);

        __syncthreads();                  // all PV reads of VH done
        if (it < 15) WRITET(cb ^ 1);
        __syncthreads();                  // staging visible
    }

    // ---- epilogue: unnormalized partials ----
    float* poA = po + (((long)half * 64 + b) * 1024 + qiA) * 64;
    float* poB = poA + 32 * 64;
#pragma unroll
    for (int sg = 0; sg < 4; ++sg) {
        *(float4*)(poA + sg * 8 + g * 4) = make_float4(oA0[4*sg+0], oA0[4*sg+1], oA0[4*sg+2], oA0[4*sg+3]);
        *(float4*)(poA + 32 + sg * 8 + g * 4) = make_float4(oA1[4*sg+0], oA1[4*sg+1], oA1[4*sg+2], oA1[4*sg+3]);
        *(float4*)(poB + sg * 8 + g * 4) = make_float4(oB0[4*sg+0], oB0[4*sg+1], oB0[4*sg+2], oB0[4*sg+3]);
        *(float4*)(poB + 32 + sg * 8 + g * 4) = make_float4(oB1[4*sg+0], oB1[4*sg+1], oB1[4*sg+2], oB1[4*sg+3]);
    }
    if (g == 0) {
        pml[((long)half * 64 + b) * 1024 + qiA] = make_float2(mA, lA);
        pml[((long)half * 64 + b) * 1024 + qiA + 32] = make_float2(mB, lB);
    }
#undef LOADT
#undef WRITET
}

// ---------------------------------------------------------------------------
// merge: combine the two KV-halves' partials.
// ---------------------------------------------------------------------------
__global__ __launch_bounds__(256) void merge_kernel(
    const float* __restrict__ po, const float2* __restrict__ pml,
    float* __restrict__ out)
{
    const int idx = blockIdx.x * 256 + threadIdx.x;   // 0..262143
    const int q = idx >> 2;
    const int part = idx & 3;
    float2 a = pml[q];
    float2 c = pml[65536 + q];
    float m = fmaxf(a.x, c.x);
    float w0 = __expf(a.x - m), w1 = __expf(c.x - m);
    float inv = 1.0f / (w0 * a.y + w1 * c.y);
    const float4* o0 = (const float4*)(po + (long)q * 64 + part * 16);
    const float4* o1 = (const float4*)(po + 4194304 + (long)q * 64 + part * 16);
    float4* op = (float4*)(out + (long)q * 64 + part * 16);
#pragma unroll
    for (int j = 0; j < 4; ++j) {
        float4 x = o0[j], y = o1[j];
        op[j] = make_float4((w0 * x.x + w1 * y.x) * inv,
                            (w0 * x.y + w1 * y.y) * inv,
                            (w0 * x.z + w1 * y.z) * inv,
                            (w0 * x.w + w1 * y.w) * inv);
    }
}

extern "C" void kernel_launch(void* const* d_in, const int* in_sizes, int n_in,
                              void* d_out, int out_size, void* d_ws, size_t ws_size,
                              hipStream_t stream) {
    const float* vectors = (const float*)d_in[0];
    const float* scalars = (const float*)d_in[1];
    const float* Wq   = (const float*)d_in[2];
    const float* Wq_s = (const float*)d_in[3];
    const float* bq_s = (const float*)d_in[4];
    const float* Wk   = (const float*)d_in[5];
    const float* Wk_s = (const float*)d_in[6];
    const float* bk_s = (const float*)d_in[7];
    const float* Wv   = (const float*)d_in[8];
    float* o = (float*)d_out;

    u16* qh  = (u16*)d_ws;                 // 16MB each
    u16* ql  = qh + 8388608;
    u16* kh  = ql + 8388608;
    u16* kl  = kh + 8388608;
    u16* vth = kl + 8388608;               // 8MB
    float* po = (float*)(vth + 4194304);   // 2*65536*64 f32 = 33.5MB
    float2* pml = (float2*)(po + 8388608); // 1MB

    prep_kernel<<<1024, 256, 0, stream>>>(vectors, scalars, Wq, Wq_s, bq_s,
                                          Wk, Wk_s, bk_s, Wv,
                                          qh, ql, kh, kl, vth);
    attn_kernel<<<1024, 128, 0, stream>>>(qh, ql, kh, kl, vth, po, pml);
    merge_kernel<<<1024, 256, 0, stream>>>(po, pml, o);
}

// Round 11
// 136.432 us; speedup vs baseline: 2.0395x; 1.2113x over previous
//
#include <hip/hip_runtime.h>
#include <math.h>

typedef float f32x16 __attribute__((ext_vector_type(16)));
typedef short bf16x8 __attribute__((ext_vector_type(8)));
typedef short bf16x4 __attribute__((ext_vector_type(4)));
typedef unsigned short u16;
typedef unsigned int u32;

#define MFMA32(a, b, c) __builtin_amdgcn_mfma_f32_32x32x16_bf16(a, b, c, 0, 0, 0)

__device__ __forceinline__ u16 f2bf(float x) {
    u32 u = __float_as_uint(x);
    u += 0x7FFFu + ((u >> 16) & 1u);
    return (u16)(u >> 16);
}
__device__ __forceinline__ float bf2f(u16 h) {
    return __uint_as_float(((u32)h) << 16);
}

// ---------------------------------------------------------------------------
// prep v11: hi/lo ONLY for vector dims (0-63); scalar dims (64-127) bf16 1-pass.
// Outputs: qh/kh [tok][128]; ql/kl [tok][64] (vec lo); vth [b][dv][1024].
// ---------------------------------------------------------------------------
__global__ __launch_bounds__(256) void prep_kernel(
    const float* __restrict__ vectors, const float* __restrict__ scalars,
    const float* __restrict__ Wq, const float* __restrict__ Wq_s, const float* __restrict__ bq_s,
    const float* __restrict__ Wk, const float* __restrict__ Wk_s, const float* __restrict__ bk_s,
    const float* __restrict__ Wv,
    u16* __restrict__ qh, u16* __restrict__ ql,
    u16* __restrict__ kh, u16* __restrict__ kl,
    u16* __restrict__ vth)
{
    __shared__ float vl[64 * 68];
    __shared__ u16 vst[64 * 66];
    __shared__ float wls[1024];

    const int t = threadIdx.x;
    const int lane = t & 63;
    const int w = t >> 6;
    const int b = blockIdx.x >> 4;
    const int n0 = (blockIdx.x & 15) << 6;
    const long tok0 = (long)b * 1024 + n0;
    const float SC = 0.07216878364870323f;   // 1/sqrt(192)

    const float4* vin = (const float4*)(vectors + tok0 * 64);
#pragma unroll
    for (int r = 0; r < 4; ++r) {
        int i4 = t + (r << 8);
        int tok = i4 >> 4, c4 = (i4 & 15) << 2;
        *(float4*)&vl[tok * 68 + c4] = vin[i4];
    }
    for (int i = t; i < 1024; i += 256) wls[i] = (i < 512) ? Wq[i] : Wk[i - 512];
    __syncthreads();

#pragma unroll
    for (int r = 0; r < 4; ++r) {
        int gi = t + (r << 8);
        float* p = &vl[(gi >> 4) * 68 + ((gi & 15) << 2)];
        float x0 = p[0], x1 = p[1], x2 = p[2], x3 = p[3];
        float nrm = x0 * x0 - x1 * x1 - x2 * x2 - x3 * x3;
        float inv = 1.0f / sqrtf(fmaxf(fabsf(nrm), 1e-5f));
        p[0] = x0 * inv; p[1] = x1 * inv; p[2] = x2 * inv; p[3] = x3 * inv;
    }
    __syncthreads();

    if (w == 0) {
        // q vec feature = lane (normalized vec * SC), hi/lo; V feature = lane
        float wrv[16];
#pragma unroll
        for (int j = 0; j < 16; ++j) wrv[j] = expf(Wv[(lane >> 2) * 16 + j]);
        const int vc = lane & 3;
        for (int tok = 0; tok < 64; ++tok) {
            float q = vl[tok * 68 + lane] * SC;
            u16 h = f2bf(q);
            qh[(tok0 + tok) * 128 + lane] = h;
            ql[(tok0 + tok) * 64 + lane] = f2bf(q - bf2f(h));
            const float* p0 = &vl[tok * 68 + vc];
            float a0 = 0.f, a1 = 0.f, a2 = 0.f, a3 = 0.f;
#pragma unroll
            for (int j = 0; j < 16; j += 4) {
                a0 = fmaf(wrv[j],     p0[j * 4],       a0);
                a1 = fmaf(wrv[j + 1], p0[(j + 1) * 4], a1);
                a2 = fmaf(wrv[j + 2], p0[(j + 2) * 4], a2);
                a3 = fmaf(wrv[j + 3], p0[(j + 3) * 4], a3);
            }
            vst[lane * 66 + tok] = f2bf((a0 + a1) + (a2 + a3));
        }
    } else if (w == 1) {
        // k vec = metric * (Wq^T Wk) @ u, hi/lo
        const int i_ = lane >> 2, c = lane & 3;
        const float mc = (c == 0) ? 1.f : -1.f;
        float wqc[32];
#pragma unroll
        for (int f = 0; f < 32; ++f) wqc[f] = wls[f * 16 + i_];
        float gr[16];
#pragma unroll
        for (int jp = 0; jp < 16; ++jp) {
            float a0 = 0.f, a1 = 0.f;
#pragma unroll
            for (int f = 0; f < 32; f += 2) {
                a0 = fmaf(wqc[f],     wls[512 + f * 16 + jp],       a0);
                a1 = fmaf(wqc[f + 1], wls[512 + (f + 1) * 16 + jp], a1);
            }
            gr[jp] = (a0 + a1) * mc;
        }
        for (int tok = 0; tok < 64; ++tok) {
            const float* p0 = &vl[tok * 68 + c];
            float a0 = 0.f, a1 = 0.f, a2 = 0.f, a3 = 0.f;
#pragma unroll
            for (int jp = 0; jp < 16; jp += 4) {
                a0 = fmaf(gr[jp],     p0[jp * 4],       a0);
                a1 = fmaf(gr[jp + 1], p0[(jp + 1) * 4], a1);
                a2 = fmaf(gr[jp + 2], p0[(jp + 2) * 4], a2);
                a3 = fmaf(gr[jp + 3], p0[(jp + 3) * 4], a3);
            }
            float a = (a0 + a1) + (a2 + a3);
            u16 h = f2bf(a);
            kh[(tok0 + tok) * 128 + lane] = h;
            kl[(tok0 + tok) * 64 + lane] = f2bf(a - bf2f(h));
        }
    } else {
        // scalar projections via MFMA, single-pass bf16 (score contribution tiny)
        const int tokbase = (w == 2) ? 0 : 32;
        const int l31 = lane & 31, g = lane >> 5;

        bf16x8 Ah[4];
        const float* xrow = scalars + (tok0 + tokbase + l31) * 64 + g * 8;
#pragma unroll
        for (int kk = 0; kk < 4; ++kk) {
            float4 x0 = *(const float4*)(xrow + kk * 16);
            float4 x1 = *(const float4*)(xrow + kk * 16 + 4);
            float xs[8] = {x0.x, x0.y, x0.z, x0.w, x1.x, x1.y, x1.z, x1.w};
#pragma unroll
            for (int e = 0; e < 8; ++e) Ah[kk][e] = (short)f2bf(xs[e]);
        }

#pragma unroll
        for (int ft = 0; ft < 4; ++ft) {
            const int isq = (ft < 2);
            const int fs = ((ft & 1) << 5) + l31;
            const float* wrow = (isq ? Wq_s : Wk_s) + fs * 64 + g * 8;
            f32x16 acc;
#pragma unroll
            for (int r = 0; r < 16; ++r) acc[r] = 0.f;
#pragma unroll
            for (int kk = 0; kk < 4; ++kk) {
                float4 w0_ = *(const float4*)(wrow + kk * 16);
                float4 w1_ = *(const float4*)(wrow + kk * 16 + 4);
                float ws_[8] = {w0_.x, w0_.y, w0_.z, w0_.w, w1_.x, w1_.y, w1_.z, w1_.w};
                bf16x8 Bh;
#pragma unroll
                for (int e = 0; e < 8; ++e) Bh[e] = (short)f2bf(ws_[e]);
                acc = MFMA32(Ah[kk], Bh, acc);
            }
            const float bias = (isq ? bq_s : bk_s)[fs];
            const float sc = isq ? SC : 1.f;
            u16* oh = isq ? qh : kh;
#pragma unroll
            for (int reg = 0; reg < 16; ++reg) {
                int trow = (reg & 3) + 8 * (reg >> 2) + 4 * g;
                oh[(tok0 + tokbase + trow) * 128 + 64 + fs] = f2bf((acc[reg] + bias) * sc);
            }
        }
    }
    __syncthreads();

#pragma unroll
    for (int r = 0; r < 8; ++r) {
        int i = t + (r << 8);
        int dv = i >> 5;
        int tp = (i & 31) << 1;
        u16 p0 = vst[dv * 66 + tp];
        u16 p1 = vst[dv * 66 + tp + 1];
        long o = ((long)b * 64 + dv) * 1024 + n0 + tp;
        *(u32*)(vth + o) = (u32)p0 | ((u32)p1 << 16);
    }
}

// ---------------------------------------------------------------------------
// attn v11: 4 waves x 32q = 128q/block, KV-split-2 (1024 blocks, 512 keys).
// QK: vec dims 3-pass hi/lo (12 MFMA) + scalar dims 1-pass (4 MFMA).
// All LDS double-buffered (34 KB), 1 barrier/iter, K XOR-swizzled.
// Target ~180 regs -> 2 waves/SIMD.
// ---------------------------------------------------------------------------
__global__ __launch_bounds__(256) void attn_kernel(
    const u16* __restrict__ qh, const u16* __restrict__ ql,
    const u16* __restrict__ kh, const u16* __restrict__ kl,
    const u16* __restrict__ vth, float* __restrict__ po,
    float2* __restrict__ pml)
{
    __shared__ u16 KH[2 * 32 * 128];   // 16 KB
    __shared__ u16 KL[2 * 32 * 64];    //  8 KB
    __shared__ u16 VH[2 * 64 * 40];    // 10 KB

    const int t = threadIdx.x;
    const int lane = t & 63;
    const int w = t >> 6;            // 0..3
    const int l31 = lane & 31, g = lane >> 5;

    const int bid = blockIdx.x;      // 0..1023
    const int xcd = bid & 7;
    const int idx = bid >> 3;        // 0..127
    const int b = xcd * 8 + (idx >> 4);
    const int qt = (idx >> 1) & 7;
    const int half = idx & 1;
    const int kv0 = half << 9;

    const int qi = qt * 128 + w * 32 + l31;
    const long qtok = (long)b * 1024 + qi;

    // ---- Q fragments: hi (8 chunks) + vec-lo (4 chunks) ----
    bf16x8 Qh[8], Qlv[4];
    {
        const u16* qhp = qh + qtok * 128 + g * 8;
        const u16* qlp = ql + qtok * 64 + g * 8;
#pragma unroll
        for (int c = 0; c < 8; ++c) Qh[c] = *(const bf16x8*)(qhp + c * 16);
#pragma unroll
        for (int c = 0; c < 4; ++c) Qlv[c] = *(const bf16x8*)(qlp + c * 16);
    }

    // ---- staging maps (256 threads) ----
    const int krow = t >> 3, ku = t & 7;          // K: 32 rows, 8 thr/row
    const u16* khg = kh + ((long)b * 1024 + kv0 + krow) * 128 + ku * 16;
    const u16* klg = kl + ((long)b * 1024 + kv0 + krow) * 64 + ku * 8;
    const int kd0 = krow * 128 + (((ku << 1)    ) ^ (krow & 15)) * 8;
    const int kd1 = krow * 128 + (((ku << 1) + 1) ^ (krow & 15)) * 8;
    const int kdl = krow * 64 + (ku ^ (krow & 7)) * 8;
    const int vdv = t >> 2, vq4 = t & 3;          // V: 64 rows, 4 thr/row
    const u16* vhg = vth + ((long)b * 64 + vdv) * 1024 + kv0 + vq4 * 8;
    u16* vdst = VH + vdv * 40 + vq4 * 8;

    int4 rk0, rk1, rl0, rv0;

#define LOADT(kt) do { \
        const u16* p1 = khg + (long)(kt) * 128; \
        rk0 = *(const int4*)(p1); rk1 = *(const int4*)(p1 + 8); \
        rl0 = *(const int4*)(klg + (long)(kt) * 64); \
        rv0 = *(const int4*)(vhg + (kt)); \
    } while (0)

#define WRITET(buf) do { \
        u16* d = KH + (buf) * 4096; \
        *(int4*)(d + kd0) = rk0; *(int4*)(d + kd1) = rk1; \
        *(int4*)(KL + (buf) * 2048 + kdl) = rl0; \
        *(int4*)(vdst + (buf) * 2560) = rv0; \
    } while (0)

    f32x16 o0, o1;
#pragma unroll
    for (int r = 0; r < 16; ++r) { o0[r] = 0.f; o1[r] = 0.f; }
    float m_run = -1e30f, l_run = 0.f;

    LOADT(0);
    WRITET(0);
    __syncthreads();

    for (int it = 0; it < 16; ++it) {
        const int cb = it & 1;
        if (it < 15) LOADT((it + 1) * 32);

        // ---- QK^T: S^T[key][q] ----
        f32x16 sA, sB;
#pragma unroll
        for (int r = 0; r < 16; ++r) { sA[r] = 0.f; sB[r] = 0.f; }
        const u16* kbh = KH + cb * 4096 + l31 * 128;
        const u16* kbl = KL + cb * 2048 + l31 * 64;
        const int rs = l31 & 15, rs7 = l31 & 7;
        __builtin_amdgcn_s_setprio(1);
#pragma unroll
        for (int c = 0; c < 4; ++c) {
            bf16x8 fh = *(const bf16x8*)(kbh + ((g + 2 * c) ^ rs) * 8);
            bf16x8 fl = *(const bf16x8*)(kbl + ((g + 2 * c) ^ rs7) * 8);
            sA = MFMA32(fh, Qh[c], sA);
            sB = MFMA32(fl, Qh[c], sB);
            sB = MFMA32(fh, Qlv[c], sB);
        }
#pragma unroll
        for (int c = 4; c < 8; ++c) {
            bf16x8 fh = *(const bf16x8*)(kbh + ((g + 2 * c) ^ rs) * 8);
            sA = MFMA32(fh, Qh[c], sA);
        }
        __builtin_amdgcn_s_setprio(0);

        // ---- online softmax with defer-max ----
        float s[16];
#pragma unroll
        for (int r = 0; r < 16; ++r) s[r] = sA[r] + sB[r];
        float mt = s[0];
#pragma unroll
        for (int r = 1; r < 16; ++r) mt = fmaxf(mt, s[r]);
        mt = fmaxf(mt, __shfl_xor(mt, 32));
        if (!__all(mt - m_run <= 8.f)) {
            float mn = fmaxf(m_run, mt);
            float corr = __expf(m_run - mn);
            l_run *= corr;
#pragma unroll
            for (int r = 0; r < 16; ++r) { o0[r] *= corr; o1[r] *= corr; }
            m_run = mn;
        }
        float ps = 0.f;
#pragma unroll
        for (int r = 0; r < 16; ++r) { s[r] = __expf(s[r] - m_run); ps += s[r]; }
        ps += __shfl_xor(ps, 32);
        l_run += ps;

        bf16x8 ph0, ph1;
#pragma unroll
        for (int e = 0; e < 8; ++e) {
            ph0[e] = (short)f2bf(s[e]);
            ph1[e] = (short)f2bf(s[8 + e]);
        }

        // ---- V fragments (pitch 40, permuted key-slot quads) ----
        const u16* vb = VH + cb * 2560;
        bf16x8 v00, v01, v10, v11;
        {
            const u16* p00 = vb + l31 * 40 + g * 4;
            const u16* p10 = vb + (32 + l31) * 40 + g * 4;
            bf16x4 a0 = *(const bf16x4*)(p00);      bf16x4 a1 = *(const bf16x4*)(p00 + 8);
            bf16x4 b0 = *(const bf16x4*)(p00 + 16); bf16x4 b1 = *(const bf16x4*)(p00 + 24);
            bf16x4 c0 = *(const bf16x4*)(p10);      bf16x4 c1 = *(const bf16x4*)(p10 + 8);
            bf16x4 d0 = *(const bf16x4*)(p10 + 16); bf16x4 d1 = *(const bf16x4*)(p10 + 24);
            v00 = __builtin_shufflevector(a0, a1, 0, 1, 2, 3, 4, 5, 6, 7);
            v01 = __builtin_shufflevector(b0, b1, 0, 1, 2, 3, 4, 5, 6, 7);
            v10 = __builtin_shufflevector(c0, c1, 0, 1, 2, 3, 4, 5, 6, 7);
            v11 = __builtin_shufflevector(d0, d1, 0, 1, 2, 3, 4, 5, 6, 7);
        }

        __builtin_amdgcn_s_setprio(1);
        o0 = MFMA32(v00, ph0, o0);
        o0 = MFMA32(v01, ph1, o0);
        o1 = MFMA32(v10, ph0, o1);
        o1 = MFMA32(v11, ph1, o1);
        __builtin_amdgcn_s_setprio(0);

        if (it < 15) WRITET(cb ^ 1);
        __syncthreads();
    }

    // ---- epilogue: unnormalized partials ----
    float* poA = po + (((long)half * 64 + b) * 1024 + qi) * 64;
#pragma unroll
    for (int sg = 0; sg < 4; ++sg) {
        *(float4*)(poA + sg * 8 + g * 4) = make_float4(
            o0[4*sg+0], o0[4*sg+1], o0[4*sg+2], o0[4*sg+3]);
        *(float4*)(poA + 32 + sg * 8 + g * 4) = make_float4(
            o1[4*sg+0], o1[4*sg+1], o1[4*sg+2], o1[4*sg+3]);
    }
    if (g == 0) {
        pml[((long)half * 64 + b) * 1024 + qi] = make_float2(m_run, l_run);
    }
#undef LOADT
#undef WRITET
}

// ---------------------------------------------------------------------------
// merge: combine the two KV-halves' partials.
// ---------------------------------------------------------------------------
__global__ __launch_bounds__(256) void merge_kernel(
    const float* __restrict__ po, const float2* __restrict__ pml,
    float* __restrict__ out)
{
    const int idx = blockIdx.x * 256 + threadIdx.x;   // 0..262143
    const int q = idx >> 2;
    const int part = idx & 3;
    float2 a = pml[q];
    float2 c = pml[65536 + q];
    float m = fmaxf(a.x, c.x);
    float w0 = __expf(a.x - m), w1 = __expf(c.x - m);
    float inv = 1.0f / (w0 * a.y + w1 * c.y);
    const float4* o0 = (const float4*)(po + (long)q * 64 + part * 16);
    const float4* o1 = (const float4*)(po + 4194304 + (long)q * 64 + part * 16);
    float4* op = (float4*)(out + (long)q * 64 + part * 16);
#pragma unroll
    for (int j = 0; j < 4; ++j) {
        float4 x = o0[j], y = o1[j];
        op[j] = make_float4((w0 * x.x + w1 * y.x) * inv,
                            (w0 * x.y + w1 * y.y) * inv,
                            (w0 * x.z + w1 * y.z) * inv,
                            (w0 * x.w + w1 * y.w) * inv);
    }
}

extern "C" void kernel_launch(void* const* d_in, const int* in_sizes, int n_in,
                              void* d_out, int out_size, void* d_ws, size_t ws_size,
                              hipStream_t stream) {
    const float* vectors = (const float*)d_in[0];
    const float* scalars = (const float*)d_in[1];
    const float* Wq   = (const float*)d_in[2];
    const float* Wq_s = (const float*)d_in[3];
    const float* bq_s = (const float*)d_in[4];
    const float* Wk   = (const float*)d_in[5];
    const float* Wk_s = (const float*)d_in[6];
    const float* bk_s = (const float*)d_in[7];
    const float* Wv   = (const float*)d_in[8];
    float* o = (float*)d_out;

    u16* qh  = (u16*)d_ws;                 // 65536*128
    u16* ql  = qh + 8388608;               // 65536*64
    u16* kh  = ql + 4194304;               // 65536*128
    u16* kl  = kh + 8388608;               // 65536*64
    u16* vth = kl + 4194304;               // 64*64*1024
    float* po = (float*)(vth + 4194304);   // 2*65536*64 f32
    float2* pml = (float2*)(po + 8388608); // 2*65536 float2

    prep_kernel<<<1024, 256, 0, stream>>>(vectors, scalars, Wq, Wq_s, bq_s,
                                          Wk, Wk_s, bk_s, Wv,
                                          qh, ql, kh, kl, vth);
    attn_kernel<<<1024, 256, 0, stream>>>(qh, ql, kh, kl, vth, po, pml);
    merge_kernel<<<1024, 256, 0, stream>>>(po, pml, o);
}

// Round 12
// 134.194 us; speedup vs baseline: 2.0735x; 1.0167x over previous
//
#include <hip/hip_runtime.h>
#include <math.h>

typedef float f32x16 __attribute__((ext_vector_type(16)));
typedef short bf16x8 __attribute__((ext_vector_type(8)));
typedef short bf16x4 __attribute__((ext_vector_type(4)));
typedef unsigned short u16;
typedef unsigned int u32;

#define MFMA32(a, b, c) __builtin_amdgcn_mfma_f32_32x32x16_bf16(a, b, c, 0, 0, 0)

__device__ __forceinline__ u16 f2bf(float x) {
    u32 u = __float_as_uint(x);
    u += 0x7FFFu + ((u >> 16) & 1u);
    return (u16)(u >> 16);
}
__device__ __forceinline__ float bf2f(u16 h) {
    return __uint_as_float(((u32)h) << 16);
}

// ---------------------------------------------------------------------------
// prep v12: 32-token blocks, 2048 blocks (2x TLP, half the serial path).
//   wave0: q vec (copy*SC, hi/lo) + V features -> vst
//   wave1: k vec = metric * (Wq^T Wk) @ u, hi/lo
//   wave2: scalar-q MFMA (32-token tile, 8 MFMA)
//   wave3: scalar-k MFMA
// Outputs: qh/kh [tok][128]; ql/kl [tok][64] (vec lo); vth [b][dv][1024].
// ---------------------------------------------------------------------------
__global__ __launch_bounds__(256) void prep_kernel(
    const float* __restrict__ vectors, const float* __restrict__ scalars,
    const float* __restrict__ Wq, const float* __restrict__ Wq_s, const float* __restrict__ bq_s,
    const float* __restrict__ Wk, const float* __restrict__ Wk_s, const float* __restrict__ bk_s,
    const float* __restrict__ Wv,
    u16* __restrict__ qh, u16* __restrict__ ql,
    u16* __restrict__ kh, u16* __restrict__ kl,
    u16* __restrict__ vth)
{
    __shared__ float vl[32 * 68];    // normalized vectors [tok][64]
    __shared__ u16 vst[64 * 34];     // v staging [dv][tok]
    __shared__ float wls[1024];      // Wq (512) | Wk (512)

    const int t = threadIdx.x;
    const int lane = t & 63;
    const int w = t >> 6;
    const int b = blockIdx.x >> 5;
    const int n0 = (blockIdx.x & 31) << 5;
    const long tok0 = (long)b * 1024 + n0;
    const float SC = 0.07216878364870323f;   // 1/sqrt(192)

    const float4* vin = (const float4*)(vectors + tok0 * 64);
#pragma unroll
    for (int r = 0; r < 2; ++r) {
        int i4 = t + (r << 8);
        int tok = i4 >> 4, c4 = (i4 & 15) << 2;
        *(float4*)&vl[tok * 68 + c4] = vin[i4];
    }
    for (int i = t; i < 1024; i += 256) wls[i] = (i < 512) ? Wq[i] : Wk[i - 512];
    __syncthreads();

#pragma unroll
    for (int r = 0; r < 2; ++r) {
        int gi = t + (r << 8);
        float* p = &vl[(gi >> 4) * 68 + ((gi & 15) << 2)];
        float x0 = p[0], x1 = p[1], x2 = p[2], x3 = p[3];
        float nrm = x0 * x0 - x1 * x1 - x2 * x2 - x3 * x3;
        float inv = 1.0f / sqrtf(fmaxf(fabsf(nrm), 1e-5f));
        p[0] = x0 * inv; p[1] = x1 * inv; p[2] = x2 * inv; p[3] = x3 * inv;
    }
    __syncthreads();

    if (w == 0) {
        // q vec feature = lane, hi/lo; V feature = lane
        float wrv[16];
#pragma unroll
        for (int j = 0; j < 16; ++j) wrv[j] = expf(Wv[(lane >> 2) * 16 + j]);
        const int vc = lane & 3;
#pragma unroll 2
        for (int tok = 0; tok < 32; ++tok) {
            float q = vl[tok * 68 + lane] * SC;
            u16 h = f2bf(q);
            qh[(tok0 + tok) * 128 + lane] = h;
            ql[(tok0 + tok) * 64 + lane] = f2bf(q - bf2f(h));
            const float* p0 = &vl[tok * 68 + vc];
            float a0 = 0.f, a1 = 0.f, a2 = 0.f, a3 = 0.f;
#pragma unroll
            for (int j = 0; j < 16; j += 4) {
                a0 = fmaf(wrv[j],     p0[j * 4],       a0);
                a1 = fmaf(wrv[j + 1], p0[(j + 1) * 4], a1);
                a2 = fmaf(wrv[j + 2], p0[(j + 2) * 4], a2);
                a3 = fmaf(wrv[j + 3], p0[(j + 3) * 4], a3);
            }
            vst[lane * 34 + tok] = f2bf((a0 + a1) + (a2 + a3));
        }
    } else if (w == 1) {
        // k vec = metric * (Wq^T Wk) @ u, hi/lo
        const int i_ = lane >> 2, c = lane & 3;
        const float mc = (c == 0) ? 1.f : -1.f;
        float wqc[32];
#pragma unroll
        for (int f = 0; f < 32; ++f) wqc[f] = wls[f * 16 + i_];
        float gr[16];
#pragma unroll
        for (int jp = 0; jp < 16; ++jp) {
            float a0 = 0.f, a1 = 0.f;
#pragma unroll
            for (int f = 0; f < 32; f += 2) {
                a0 = fmaf(wqc[f],     wls[512 + f * 16 + jp],       a0);
                a1 = fmaf(wqc[f + 1], wls[512 + (f + 1) * 16 + jp], a1);
            }
            gr[jp] = (a0 + a1) * mc;
        }
#pragma unroll 2
        for (int tok = 0; tok < 32; ++tok) {
            const float* p0 = &vl[tok * 68 + c];
            float a0 = 0.f, a1 = 0.f, a2 = 0.f, a3 = 0.f;
#pragma unroll
            for (int jp = 0; jp < 16; jp += 4) {
                a0 = fmaf(gr[jp],     p0[jp * 4],       a0);
                a1 = fmaf(gr[jp + 1], p0[(jp + 1) * 4], a1);
                a2 = fmaf(gr[jp + 2], p0[(jp + 2) * 4], a2);
                a3 = fmaf(gr[jp + 3], p0[(jp + 3) * 4], a3);
            }
            float a = (a0 + a1) + (a2 + a3);
            u16 h = f2bf(a);
            kh[(tok0 + tok) * 128 + lane] = h;
            kl[(tok0 + tok) * 64 + lane] = f2bf(a - bf2f(h));
        }
    } else {
        // scalar projections via MFMA, single-pass bf16 (w2: q, w3: k)
        const int isq = (w == 2);
        const int l31 = lane & 31, g = lane >> 5;

        bf16x8 Ah[4];
        const float* xrow = scalars + (tok0 + l31) * 64 + g * 8;
#pragma unroll
        for (int kk = 0; kk < 4; ++kk) {
            float4 x0 = *(const float4*)(xrow + kk * 16);
            float4 x1 = *(const float4*)(xrow + kk * 16 + 4);
            float xs[8] = {x0.x, x0.y, x0.z, x0.w, x1.x, x1.y, x1.z, x1.w};
#pragma unroll
            for (int e = 0; e < 8; ++e) Ah[kk][e] = (short)f2bf(xs[e]);
        }

        const float sc = isq ? SC : 1.f;
        u16* oh = isq ? qh : kh;
#pragma unroll
        for (int ft = 0; ft < 2; ++ft) {
            const int fs = (ft << 5) + l31;
            const float* wrow = (isq ? Wq_s : Wk_s) + fs * 64 + g * 8;
            f32x16 acc;
#pragma unroll
            for (int r = 0; r < 16; ++r) acc[r] = 0.f;
#pragma unroll
            for (int kk = 0; kk < 4; ++kk) {
                float4 w0_ = *(const float4*)(wrow + kk * 16);
                float4 w1_ = *(const float4*)(wrow + kk * 16 + 4);
                float ws_[8] = {w0_.x, w0_.y, w0_.z, w0_.w, w1_.x, w1_.y, w1_.z, w1_.w};
                bf16x8 Bh;
#pragma unroll
                for (int e = 0; e < 8; ++e) Bh[e] = (short)f2bf(ws_[e]);
                acc = MFMA32(Ah[kk], Bh, acc);
            }
            const float bias = (isq ? bq_s : bk_s)[fs];
#pragma unroll
            for (int reg = 0; reg < 16; ++reg) {
                int trow = (reg & 3) + 8 * (reg >> 2) + 4 * g;
                oh[(tok0 + trow) * 128 + 64 + fs] = f2bf((acc[reg] + bias) * sc);
            }
        }
    }
    __syncthreads();

    // coalesced v copy-out: 64 dv x 32 tok as u32 pairs (1024 u32)
#pragma unroll
    for (int r = 0; r < 4; ++r) {
        int i = t + (r << 8);            // 0..1023
        int dv = i >> 4;                 // 0..63
        int tp = (i & 15) << 1;          // 0,2,..,30
        u16 p0 = vst[dv * 34 + tp];
        u16 p1 = vst[dv * 34 + tp + 1];
        long o = ((long)b * 64 + dv) * 1024 + n0 + tp;
        *(u32*)(vth + o) = (u32)p0 | ((u32)p1 << 16);
    }
}

// ---------------------------------------------------------------------------
// attn v11 (unchanged): 4 waves x 32q, KV-split-2, mixed hi/lo QK.
// ---------------------------------------------------------------------------
__global__ __launch_bounds__(256) void attn_kernel(
    const u16* __restrict__ qh, const u16* __restrict__ ql,
    const u16* __restrict__ kh, const u16* __restrict__ kl,
    const u16* __restrict__ vth, float* __restrict__ po,
    float2* __restrict__ pml)
{
    __shared__ u16 KH[2 * 32 * 128];   // 16 KB
    __shared__ u16 KL[2 * 32 * 64];    //  8 KB
    __shared__ u16 VH[2 * 64 * 40];    // 10 KB

    const int t = threadIdx.x;
    const int lane = t & 63;
    const int w = t >> 6;            // 0..3
    const int l31 = lane & 31, g = lane >> 5;

    const int bid = blockIdx.x;      // 0..1023
    const int xcd = bid & 7;
    const int idx = bid >> 3;        // 0..127
    const int b = xcd * 8 + (idx >> 4);
    const int qt = (idx >> 1) & 7;
    const int half = idx & 1;
    const int kv0 = half << 9;

    const int qi = qt * 128 + w * 32 + l31;
    const long qtok = (long)b * 1024 + qi;

    bf16x8 Qh[8], Qlv[4];
    {
        const u16* qhp = qh + qtok * 128 + g * 8;
        const u16* qlp = ql + qtok * 64 + g * 8;
#pragma unroll
        for (int c = 0; c < 8; ++c) Qh[c] = *(const bf16x8*)(qhp + c * 16);
#pragma unroll
        for (int c = 0; c < 4; ++c) Qlv[c] = *(const bf16x8*)(qlp + c * 16);
    }

    const int krow = t >> 3, ku = t & 7;
    const u16* khg = kh + ((long)b * 1024 + kv0 + krow) * 128 + ku * 16;
    const u16* klg = kl + ((long)b * 1024 + kv0 + krow) * 64 + ku * 8;
    const int kd0 = krow * 128 + (((ku << 1)    ) ^ (krow & 15)) * 8;
    const int kd1 = krow * 128 + (((ku << 1) + 1) ^ (krow & 15)) * 8;
    const int kdl = krow * 64 + (ku ^ (krow & 7)) * 8;
    const int vdv = t >> 2, vq4 = t & 3;
    const u16* vhg = vth + ((long)b * 64 + vdv) * 1024 + kv0 + vq4 * 8;
    u16* vdst = VH + vdv * 40 + vq4 * 8;

    int4 rk0, rk1, rl0, rv0;

#define LOADT(kt) do { \
        const u16* p1 = khg + (long)(kt) * 128; \
        rk0 = *(const int4*)(p1); rk1 = *(const int4*)(p1 + 8); \
        rl0 = *(const int4*)(klg + (long)(kt) * 64); \
        rv0 = *(const int4*)(vhg + (kt)); \
    } while (0)

#define WRITET(buf) do { \
        u16* d = KH + (buf) * 4096; \
        *(int4*)(d + kd0) = rk0; *(int4*)(d + kd1) = rk1; \
        *(int4*)(KL + (buf) * 2048 + kdl) = rl0; \
        *(int4*)(vdst + (buf) * 2560) = rv0; \
    } while (0)

    f32x16 o0, o1;
#pragma unroll
    for (int r = 0; r < 16; ++r) { o0[r] = 0.f; o1[r] = 0.f; }
    float m_run = -1e30f, l_run = 0.f;

    LOADT(0);
    WRITET(0);
    __syncthreads();

    for (int it = 0; it < 16; ++it) {
        const int cb = it & 1;
        if (it < 15) LOADT((it + 1) * 32);

        f32x16 sA, sB;
#pragma unroll
        for (int r = 0; r < 16; ++r) { sA[r] = 0.f; sB[r] = 0.f; }
        const u16* kbh = KH + cb * 4096 + l31 * 128;
        const u16* kbl = KL + cb * 2048 + l31 * 64;
        const int rs = l31 & 15, rs7 = l31 & 7;
        __builtin_amdgcn_s_setprio(1);
#pragma unroll
        for (int c = 0; c < 4; ++c) {
            bf16x8 fh = *(const bf16x8*)(kbh + ((g + 2 * c) ^ rs) * 8);
            bf16x8 fl = *(const bf16x8*)(kbl + ((g + 2 * c) ^ rs7) * 8);
            sA = MFMA32(fh, Qh[c], sA);
            sB = MFMA32(fl, Qh[c], sB);
            sB = MFMA32(fh, Qlv[c], sB);
        }
#pragma unroll
        for (int c = 4; c < 8; ++c) {
            bf16x8 fh = *(const bf16x8*)(kbh + ((g + 2 * c) ^ rs) * 8);
            sA = MFMA32(fh, Qh[c], sA);
        }
        __builtin_amdgcn_s_setprio(0);

        float s[16];
#pragma unroll
        for (int r = 0; r < 16; ++r) s[r] = sA[r] + sB[r];
        float mt = s[0];
#pragma unroll
        for (int r = 1; r < 16; ++r) mt = fmaxf(mt, s[r]);
        mt = fmaxf(mt, __shfl_xor(mt, 32));
        if (!__all(mt - m_run <= 8.f)) {
            float mn = fmaxf(m_run, mt);
            float corr = __expf(m_run - mn);
            l_run *= corr;
#pragma unroll
            for (int r = 0; r < 16; ++r) { o0[r] *= corr; o1[r] *= corr; }
            m_run = mn;
        }
        float ps = 0.f;
#pragma unroll
        for (int r = 0; r < 16; ++r) { s[r] = __expf(s[r] - m_run); ps += s[r]; }
        ps += __shfl_xor(ps, 32);
        l_run += ps;

        bf16x8 ph0, ph1;
#pragma unroll
        for (int e = 0; e < 8; ++e) {
            ph0[e] = (short)f2bf(s[e]);
            ph1[e] = (short)f2bf(s[8 + e]);
        }

        const u16* vb = VH + cb * 2560;
        bf16x8 v00, v01, v10, v11;
        {
            const u16* p00 = vb + l31 * 40 + g * 4;
            const u16* p10 = vb + (32 + l31) * 40 + g * 4;
            bf16x4 a0 = *(const bf16x4*)(p00);      bf16x4 a1 = *(const bf16x4*)(p00 + 8);
            bf16x4 b0 = *(const bf16x4*)(p00 + 16); bf16x4 b1 = *(const bf16x4*)(p00 + 24);
            bf16x4 c0 = *(const bf16x4*)(p10);      bf16x4 c1 = *(const bf16x4*)(p10 + 8);
            bf16x4 d0 = *(const bf16x4*)(p10 + 16); bf16x4 d1 = *(const bf16x4*)(p10 + 24);
            v00 = __builtin_shufflevector(a0, a1, 0, 1, 2, 3, 4, 5, 6, 7);
            v01 = __builtin_shufflevector(b0, b1, 0, 1, 2, 3, 4, 5, 6, 7);
            v10 = __builtin_shufflevector(c0, c1, 0, 1, 2, 3, 4, 5, 6, 7);
            v11 = __builtin_shufflevector(d0, d1, 0, 1, 2, 3, 4, 5, 6, 7);
        }

        __builtin_amdgcn_s_setprio(1);
        o0 = MFMA32(v00, ph0, o0);
        o0 = MFMA32(v01, ph1, o0);
        o1 = MFMA32(v10, ph0, o1);
        o1 = MFMA32(v11, ph1, o1);
        __builtin_amdgcn_s_setprio(0);

        if (it < 15) WRITET(cb ^ 1);
        __syncthreads();
    }

    float* poA = po + (((long)half * 64 + b) * 1024 + qi) * 64;
#pragma unroll
    for (int sg = 0; sg < 4; ++sg) {
        *(float4*)(poA + sg * 8 + g * 4) = make_float4(
            o0[4*sg+0], o0[4*sg+1], o0[4*sg+2], o0[4*sg+3]);
        *(float4*)(poA + 32 + sg * 8 + g * 4) = make_float4(
            o1[4*sg+0], o1[4*sg+1], o1[4*sg+2], o1[4*sg+3]);
    }
    if (g == 0) {
        pml[((long)half * 64 + b) * 1024 + qi] = make_float2(m_run, l_run);
    }
#undef LOADT
#undef WRITET
}

// ---------------------------------------------------------------------------
// merge (unchanged): combine the two KV-halves' partials.
// ---------------------------------------------------------------------------
__global__ __launch_bounds__(256) void merge_kernel(
    const float* __restrict__ po, const float2* __restrict__ pml,
    float* __restrict__ out)
{
    const int idx = blockIdx.x * 256 + threadIdx.x;   // 0..262143
    const int q = idx >> 2;
    const int part = idx & 3;
    float2 a = pml[q];
    float2 c = pml[65536 + q];
    float m = fmaxf(a.x, c.x);
    float w0 = __expf(a.x - m), w1 = __expf(c.x - m);
    float inv = 1.0f / (w0 * a.y + w1 * c.y);
    const float4* o0 = (const float4*)(po + (long)q * 64 + part * 16);
    const float4* o1 = (const float4*)(po + 4194304 + (long)q * 64 + part * 16);
    float4* op = (float4*)(out + (long)q * 64 + part * 16);
#pragma unroll
    for (int j = 0; j < 4; ++j) {
        float4 x = o0[j], y = o1[j];
        op[j] = make_float4((w0 * x.x + w1 * y.x) * inv,
                            (w0 * x.y + w1 * y.y) * inv,
                            (w0 * x.z + w1 * y.z) * inv,
                            (w0 * x.w + w1 * y.w) * inv);
    }
}

extern "C" void kernel_launch(void* const* d_in, const int* in_sizes, int n_in,
                              void* d_out, int out_size, void* d_ws, size_t ws_size,
                              hipStream_t stream) {
    const float* vectors = (const float*)d_in[0];
    const float* scalars = (const float*)d_in[1];
    const float* Wq   = (const float*)d_in[2];
    const float* Wq_s = (const float*)d_in[3];
    const float* bq_s = (const float*)d_in[4];
    const float* Wk   = (const float*)d_in[5];
    const float* Wk_s = (const float*)d_in[6];
    const float* bk_s = (const float*)d_in[7];
    const float* Wv   = (const float*)d_in[8];
    float* o = (float*)d_out;

    u16* qh  = (u16*)d_ws;                 // 65536*128
    u16* ql  = qh + 8388608;               // 65536*64
    u16* kh  = ql + 4194304;               // 65536*128
    u16* kl  = kh + 8388608;               // 65536*64
    u16* vth = kl + 4194304;               // 64*64*1024
    float* po = (float*)(vth + 4194304);   // 2*65536*64 f32
    float2* pml = (float2*)(po + 8388608); // 2*65536 float2

    prep_kernel<<<2048, 256, 0, stream>>>(vectors, scalars, Wq, Wq_s, bq_s,
                                          Wk, Wk_s, bk_s, Wv,
                                          qh, ql, kh, kl, vth);
    attn_kernel<<<1024, 256, 0, stream>>>(qh, ql, kh, kl, vth, po, pml);
    merge_kernel<<<1024, 256, 0, stream>>>(po, pml, o);
}

// Round 13
// 107.084 us; speedup vs baseline: 2.5984x; 1.2532x over previous
//
#include <hip/hip_runtime.h>
#include <math.h>

typedef float f32x16 __attribute__((ext_vector_type(16)));
typedef short bf16x8 __attribute__((ext_vector_type(8)));
typedef short bf16x4 __attribute__((ext_vector_type(4)));
typedef unsigned short u16;
typedef unsigned int u32;

#define MFMA32(a, b, c) __builtin_amdgcn_mfma_f32_32x32x16_bf16(a, b, c, 0, 0, 0)

__device__ __forceinline__ u16 f2bf(float x) {
    u32 u = __float_as_uint(x);
    u += 0x7FFFu + ((u >> 16) & 1u);
    return (u16)(u >> 16);
}
__device__ __forceinline__ float bf2f(u16 h) {
    return __uint_as_float(((u32)h) << 16);
}

// ---------------------------------------------------------------------------
// g_kernel: build 64x64 component-block matrices once, bf16 hi/lo planes.
//   Gm[f][f'] = delta_{c,c'} * metric(c) * (Wq^T Wk)[j][jp]   (f=j*4+c)
//   Mv[f][f'] = delta_{c,c'} * exp(Wv)[i][jj]
// ---------------------------------------------------------------------------
__global__ __launch_bounds__(256) void g_kernel(
    const float* __restrict__ Wq, const float* __restrict__ Wk,
    const float* __restrict__ Wv,
    u16* __restrict__ gmh, u16* __restrict__ gml,
    u16* __restrict__ mvh, u16* __restrict__ mvl)
{
    const int bk = blockIdx.x;                       // 0..7
    const int base = ((bk & 3) * 256 + threadIdx.x) * 4;
    if (bk < 4) {
#pragma unroll
        for (int i = 0; i < 4; ++i) {
            int e = base + i;
            int f = e >> 6, fp = e & 63;
            int c = f & 3, cp = fp & 3, j = f >> 2, jp = fp >> 2;
            float val = 0.f;
            if (c == cp) {
                float a0 = 0.f, a1 = 0.f;
#pragma unroll 8
                for (int ff = 0; ff < 32; ff += 2) {
                    a0 = fmaf(Wq[ff * 16 + j],       Wk[ff * 16 + jp],       a0);
                    a1 = fmaf(Wq[(ff + 1) * 16 + j], Wk[(ff + 1) * 16 + jp], a1);
                }
                val = (a0 + a1) * ((c == 0) ? 1.f : -1.f);
            }
            u16 h = f2bf(val);
            gmh[e] = h; gml[e] = f2bf(val - bf2f(h));
        }
    } else {
#pragma unroll
        for (int i = 0; i < 4; ++i) {
            int e = base + i;
            int f = e >> 6, fp = e & 63;
            float val = ((f & 3) == (fp & 3)) ? expf(Wv[(f >> 2) * 16 + (fp >> 2)]) : 0.f;
            u16 h = f2bf(val);
            mvh[e] = h; mvl[e] = f2bf(val - bf2f(h));
        }
    }
}

// ---------------------------------------------------------------------------
// prep v13: all-MFMA, zero LDS, zero barriers. 2048 blocks x 32 tokens.
//   wave0: q vec copy (normalize*SC, hi/lo) + scalar-q MFMA
//   wave1: k vec MFMA (A=u hi/lo, B=Gm hi/lo, 3-pass)
//   wave2: v MFMA (A=u hi/lo, B=Mv hi/lo, 3-pass), hi-only output
//   wave3: scalar-k MFMA
// ---------------------------------------------------------------------------
__global__ __launch_bounds__(256) void prep_kernel(
    const float* __restrict__ vectors, const float* __restrict__ scalars,
    const float* __restrict__ Wq_s, const float* __restrict__ bq_s,
    const float* __restrict__ Wk_s, const float* __restrict__ bk_s,
    const u16* __restrict__ gmh, const u16* __restrict__ gml,
    const u16* __restrict__ mvh, const u16* __restrict__ mvl,
    u16* __restrict__ qh, u16* __restrict__ ql,
    u16* __restrict__ kh, u16* __restrict__ kl,
    u16* __restrict__ vth)
{
    const int t = threadIdx.x;
    const int w = t >> 6;
    const int lane = t & 63;
    const int l31 = lane & 31, g = lane >> 5;
    const int b = blockIdx.x >> 5;
    const int n0 = (blockIdx.x & 31) << 5;
    const long tok0 = (long)b * 1024 + n0;
    const float SC = 0.07216878364870323f;   // 1/sqrt(192)

    if (w == 1 || w == 2) {
        // ---- u fragments: load token row, normalize per-4-vector, hi/lo ----
        bf16x8 Ah[4], Al[4];
        const float* vrow = vectors + (tok0 + l31) * 64 + g * 8;
#pragma unroll
        for (int kk = 0; kk < 4; ++kk) {
            float4 x0 = *(const float4*)(vrow + kk * 16);
            float4 x1 = *(const float4*)(vrow + kk * 16 + 4);
            float nr0 = x0.x * x0.x - x0.y * x0.y - x0.z * x0.z - x0.w * x0.w;
            float iv0 = 1.0f / sqrtf(fmaxf(fabsf(nr0), 1e-5f));
            float nr1 = x1.x * x1.x - x1.y * x1.y - x1.z * x1.z - x1.w * x1.w;
            float iv1 = 1.0f / sqrtf(fmaxf(fabsf(nr1), 1e-5f));
            float xs[8] = {x0.x * iv0, x0.y * iv0, x0.z * iv0, x0.w * iv0,
                           x1.x * iv1, x1.y * iv1, x1.z * iv1, x1.w * iv1};
#pragma unroll
            for (int e = 0; e < 8; ++e) {
                u16 h = f2bf(xs[e]);
                Ah[kk][e] = (short)h;
                Al[kk][e] = (short)f2bf(xs[e] - bf2f(h));
            }
        }

        const u16* bhp = (w == 1) ? gmh : mvh;
        const u16* blp = (w == 1) ? gml : mvl;
#pragma unroll
        for (int tile = 0; tile < 2; ++tile) {
            const int fs = tile * 32 + l31;
            const u16* bh = bhp + fs * 64 + g * 8;
            const u16* bl = blp + fs * 64 + g * 8;
            f32x16 acc;
#pragma unroll
            for (int r = 0; r < 16; ++r) acc[r] = 0.f;
#pragma unroll
            for (int kk = 0; kk < 4; ++kk) {
                bf16x8 Bh = *(const bf16x8*)(bh + kk * 16);
                bf16x8 Bl = *(const bf16x8*)(bl + kk * 16);
                acc = MFMA32(Ah[kk], Bh, acc);
                acc = MFMA32(Al[kk], Bh, acc);
                acc = MFMA32(Ah[kk], Bl, acc);
            }
            if (w == 1) {
#pragma unroll
                for (int reg = 0; reg < 16; ++reg) {
                    int trow = (reg & 3) + 8 * (reg >> 2) + 4 * g;
                    float val = acc[reg];
                    u16 h = f2bf(val);
                    kh[(tok0 + trow) * 128 + fs] = h;
                    kl[(tok0 + trow) * 64 + fs] = f2bf(val - bf2f(h));
                }
            } else {
#pragma unroll
                for (int reg = 0; reg < 16; ++reg) {
                    int trow = (reg & 3) + 8 * (reg >> 2) + 4 * g;
                    vth[((long)b * 64 + fs) * 1024 + n0 + trow] = f2bf(acc[reg]);
                }
            }
        }
    } else {
        if (w == 0) {
            // ---- q vec copy: normalize, *SC, hi/lo, contiguous b128 stores ----
            const float* vrow = vectors + (tok0 + l31) * 64 + g * 8;
#pragma unroll
            for (int kk = 0; kk < 4; ++kk) {
                float4 x0 = *(const float4*)(vrow + kk * 16);
                float4 x1 = *(const float4*)(vrow + kk * 16 + 4);
                float nr0 = x0.x * x0.x - x0.y * x0.y - x0.z * x0.z - x0.w * x0.w;
                float iv0 = SC / sqrtf(fmaxf(fabsf(nr0), 1e-5f));
                float nr1 = x1.x * x1.x - x1.y * x1.y - x1.z * x1.z - x1.w * x1.w;
                float iv1 = SC / sqrtf(fmaxf(fabsf(nr1), 1e-5f));
                float xs[8] = {x0.x * iv0, x0.y * iv0, x0.z * iv0, x0.w * iv0,
                               x1.x * iv1, x1.y * iv1, x1.z * iv1, x1.w * iv1};
                u16 hh[8], ll[8];
#pragma unroll
                for (int e = 0; e < 8; ++e) {
                    hh[e] = f2bf(xs[e]);
                    ll[e] = f2bf(xs[e] - bf2f(hh[e]));
                }
                *(int4*)(qh + (tok0 + l31) * 128 + kk * 16 + g * 8) = *(int4*)hh;
                *(int4*)(ql + (tok0 + l31) * 64 + kk * 16 + g * 8) = *(int4*)ll;
            }
        }
        // ---- scalar projections via MFMA (w0: q, w3: k) ----
        const int isq = (w == 0);
        bf16x8 Ah[4];
        const float* xrow = scalars + (tok0 + l31) * 64 + g * 8;
#pragma unroll
        for (int kk = 0; kk < 4; ++kk) {
            float4 x0 = *(const float4*)(xrow + kk * 16);
            float4 x1 = *(const float4*)(xrow + kk * 16 + 4);
            float xs[8] = {x0.x, x0.y, x0.z, x0.w, x1.x, x1.y, x1.z, x1.w};
#pragma unroll
            for (int e = 0; e < 8; ++e) Ah[kk][e] = (short)f2bf(xs[e]);
        }
        const float sc = isq ? SC : 1.f;
        u16* oh = isq ? qh : kh;
#pragma unroll
        for (int ft = 0; ft < 2; ++ft) {
            const int fs = (ft << 5) + l31;
            const float* wrow = (isq ? Wq_s : Wk_s) + fs * 64 + g * 8;
            f32x16 acc;
#pragma unroll
            for (int r = 0; r < 16; ++r) acc[r] = 0.f;
#pragma unroll
            for (int kk = 0; kk < 4; ++kk) {
                float4 w0_ = *(const float4*)(wrow + kk * 16);
                float4 w1_ = *(const float4*)(wrow + kk * 16 + 4);
                float ws_[8] = {w0_.x, w0_.y, w0_.z, w0_.w, w1_.x, w1_.y, w1_.z, w1_.w};
                bf16x8 Bh;
#pragma unroll
                for (int e = 0; e < 8; ++e) Bh[e] = (short)f2bf(ws_[e]);
                acc = MFMA32(Ah[kk], Bh, acc);
            }
            const float bias = (isq ? bq_s : bk_s)[fs];
#pragma unroll
            for (int reg = 0; reg < 16; ++reg) {
                int trow = (reg & 3) + 8 * (reg >> 2) + 4 * g;
                oh[(tok0 + trow) * 128 + 64 + fs] = f2bf((acc[reg] + bias) * sc);
            }
        }
    }
}

// ---------------------------------------------------------------------------
// attn v11 (unchanged): 4 waves x 32q, KV-split-2, mixed hi/lo QK.
// ---------------------------------------------------------------------------
__global__ __launch_bounds__(256) void attn_kernel(
    const u16* __restrict__ qh, const u16* __restrict__ ql,
    const u16* __restrict__ kh, const u16* __restrict__ kl,
    const u16* __restrict__ vth, float* __restrict__ po,
    float2* __restrict__ pml)
{
    __shared__ u16 KH[2 * 32 * 128];   // 16 KB
    __shared__ u16 KL[2 * 32 * 64];    //  8 KB
    __shared__ u16 VH[2 * 64 * 40];    // 10 KB

    const int t = threadIdx.x;
    const int lane = t & 63;
    const int w = t >> 6;            // 0..3
    const int l31 = lane & 31, g = lane >> 5;

    const int bid = blockIdx.x;      // 0..1023
    const int xcd = bid & 7;
    const int idx = bid >> 3;        // 0..127
    const int b = xcd * 8 + (idx >> 4);
    const int qt = (idx >> 1) & 7;
    const int half = idx & 1;
    const int kv0 = half << 9;

    const int qi = qt * 128 + w * 32 + l31;
    const long qtok = (long)b * 1024 + qi;

    bf16x8 Qh[8], Qlv[4];
    {
        const u16* qhp = qh + qtok * 128 + g * 8;
        const u16* qlp = ql + qtok * 64 + g * 8;
#pragma unroll
        for (int c = 0; c < 8; ++c) Qh[c] = *(const bf16x8*)(qhp + c * 16);
#pragma unroll
        for (int c = 0; c < 4; ++c) Qlv[c] = *(const bf16x8*)(qlp + c * 16);
    }

    const int krow = t >> 3, ku = t & 7;
    const u16* khg = kh + ((long)b * 1024 + kv0 + krow) * 128 + ku * 16;
    const u16* klg = kl + ((long)b * 1024 + kv0 + krow) * 64 + ku * 8;
    const int kd0 = krow * 128 + (((ku << 1)    ) ^ (krow & 15)) * 8;
    const int kd1 = krow * 128 + (((ku << 1) + 1) ^ (krow & 15)) * 8;
    const int kdl = krow * 64 + (ku ^ (krow & 7)) * 8;
    const int vdv = t >> 2, vq4 = t & 3;
    const u16* vhg = vth + ((long)b * 64 + vdv) * 1024 + kv0 + vq4 * 8;
    u16* vdst = VH + vdv * 40 + vq4 * 8;

    int4 rk0, rk1, rl0, rv0;

#define LOADT(kt) do { \
        const u16* p1 = khg + (long)(kt) * 128; \
        rk0 = *(const int4*)(p1); rk1 = *(const int4*)(p1 + 8); \
        rl0 = *(const int4*)(klg + (long)(kt) * 64); \
        rv0 = *(const int4*)(vhg + (kt)); \
    } while (0)

#define WRITET(buf) do { \
        u16* d = KH + (buf) * 4096; \
        *(int4*)(d + kd0) = rk0; *(int4*)(d + kd1) = rk1; \
        *(int4*)(KL + (buf) * 2048 + kdl) = rl0; \
        *(int4*)(vdst + (buf) * 2560) = rv0; \
    } while (0)

    f32x16 o0, o1;
#pragma unroll
    for (int r = 0; r < 16; ++r) { o0[r] = 0.f; o1[r] = 0.f; }
    float m_run = -1e30f, l_run = 0.f;

    LOADT(0);
    WRITET(0);
    __syncthreads();

    for (int it = 0; it < 16; ++it) {
        const int cb = it & 1;
        if (it < 15) LOADT((it + 1) * 32);

        f32x16 sA, sB;
#pragma unroll
        for (int r = 0; r < 16; ++r) { sA[r] = 0.f; sB[r] = 0.f; }
        const u16* kbh = KH + cb * 4096 + l31 * 128;
        const u16* kbl = KL + cb * 2048 + l31 * 64;
        const int rs = l31 & 15, rs7 = l31 & 7;
        __builtin_amdgcn_s_setprio(1);
#pragma unroll
        for (int c = 0; c < 4; ++c) {
            bf16x8 fh = *(const bf16x8*)(kbh + ((g + 2 * c) ^ rs) * 8);
            bf16x8 fl = *(const bf16x8*)(kbl + ((g + 2 * c) ^ rs7) * 8);
            sA = MFMA32(fh, Qh[c], sA);
            sB = MFMA32(fl, Qh[c], sB);
            sB = MFMA32(fh, Qlv[c], sB);
        }
#pragma unroll
        for (int c = 4; c < 8; ++c) {
            bf16x8 fh = *(const bf16x8*)(kbh + ((g + 2 * c) ^ rs) * 8);
            sA = MFMA32(fh, Qh[c], sA);
        }
        __builtin_amdgcn_s_setprio(0);

        float s[16];
#pragma unroll
        for (int r = 0; r < 16; ++r) s[r] = sA[r] + sB[r];
        float mt = s[0];
#pragma unroll
        for (int r = 1; r < 16; ++r) mt = fmaxf(mt, s[r]);
        mt = fmaxf(mt, __shfl_xor(mt, 32));
        if (!__all(mt - m_run <= 8.f)) {
            float mn = fmaxf(m_run, mt);
            float corr = __expf(m_run - mn);
            l_run *= corr;
#pragma unroll
            for (int r = 0; r < 16; ++r) { o0[r] *= corr; o1[r] *= corr; }
            m_run = mn;
        }
        float ps = 0.f;
#pragma unroll
        for (int r = 0; r < 16; ++r) { s[r] = __expf(s[r] - m_run); ps += s[r]; }
        ps += __shfl_xor(ps, 32);
        l_run += ps;

        bf16x8 ph0, ph1;
#pragma unroll
        for (int e = 0; e < 8; ++e) {
            ph0[e] = (short)f2bf(s[e]);
            ph1[e] = (short)f2bf(s[8 + e]);
        }

        const u16* vb = VH + cb * 2560;
        bf16x8 v00, v01, v10, v11;
        {
            const u16* p00 = vb + l31 * 40 + g * 4;
            const u16* p10 = vb + (32 + l31) * 40 + g * 4;
            bf16x4 a0 = *(const bf16x4*)(p00);      bf16x4 a1 = *(const bf16x4*)(p00 + 8);
            bf16x4 b0 = *(const bf16x4*)(p00 + 16); bf16x4 b1 = *(const bf16x4*)(p00 + 24);
            bf16x4 c0 = *(const bf16x4*)(p10);      bf16x4 c1 = *(const bf16x4*)(p10 + 8);
            bf16x4 d0 = *(const bf16x4*)(p10 + 16); bf16x4 d1 = *(const bf16x4*)(p10 + 24);
            v00 = __builtin_shufflevector(a0, a1, 0, 1, 2, 3, 4, 5, 6, 7);
            v01 = __builtin_shufflevector(b0, b1, 0, 1, 2, 3, 4, 5, 6, 7);
            v10 = __builtin_shufflevector(c0, c1, 0, 1, 2, 3, 4, 5, 6, 7);
            v11 = __builtin_shufflevector(d0, d1, 0, 1, 2, 3, 4, 5, 6, 7);
        }

        __builtin_amdgcn_s_setprio(1);
        o0 = MFMA32(v00, ph0, o0);
        o0 = MFMA32(v01, ph1, o0);
        o1 = MFMA32(v10, ph0, o1);
        o1 = MFMA32(v11, ph1, o1);
        __builtin_amdgcn_s_setprio(0);

        if (it < 15) WRITET(cb ^ 1);
        __syncthreads();
    }

    float* poA = po + (((long)half * 64 + b) * 1024 + qi) * 64;
#pragma unroll
    for (int sg = 0; sg < 4; ++sg) {
        *(float4*)(poA + sg * 8 + g * 4) = make_float4(
            o0[4*sg+0], o0[4*sg+1], o0[4*sg+2], o0[4*sg+3]);
        *(float4*)(poA + 32 + sg * 8 + g * 4) = make_float4(
            o1[4*sg+0], o1[4*sg+1], o1[4*sg+2], o1[4*sg+3]);
    }
    if (g == 0) {
        pml[((long)half * 64 + b) * 1024 + qi] = make_float2(m_run, l_run);
    }
#undef LOADT
#undef WRITET
}

// ---------------------------------------------------------------------------
// merge (unchanged): combine the two KV-halves' partials.
// ---------------------------------------------------------------------------
__global__ __launch_bounds__(256) void merge_kernel(
    const float* __restrict__ po, const float2* __restrict__ pml,
    float* __restrict__ out)
{
    const int idx = blockIdx.x * 256 + threadIdx.x;   // 0..262143
    const int q = idx >> 2;
    const int part = idx & 3;
    float2 a = pml[q];
    float2 c = pml[65536 + q];
    float m = fmaxf(a.x, c.x);
    float w0 = __expf(a.x - m), w1 = __expf(c.x - m);
    float inv = 1.0f / (w0 * a.y + w1 * c.y);
    const float4* o0 = (const float4*)(po + (long)q * 64 + part * 16);
    const float4* o1 = (const float4*)(po + 4194304 + (long)q * 64 + part * 16);
    float4* op = (float4*)(out + (long)q * 64 + part * 16);
#pragma unroll
    for (int j = 0; j < 4; ++j) {
        float4 x = o0[j], y = o1[j];
        op[j] = make_float4((w0 * x.x + w1 * y.x) * inv,
                            (w0 * x.y + w1 * y.y) * inv,
                            (w0 * x.z + w1 * y.z) * inv,
                            (w0 * x.w + w1 * y.w) * inv);
    }
}

extern "C" void kernel_launch(void* const* d_in, const int* in_sizes, int n_in,
                              void* d_out, int out_size, void* d_ws, size_t ws_size,
                              hipStream_t stream) {
    const float* vectors = (const float*)d_in[0];
    const float* scalars = (const float*)d_in[1];
    const float* Wq   = (const float*)d_in[2];
    const float* Wq_s = (const float*)d_in[3];
    const float* bq_s = (const float*)d_in[4];
    const float* Wk   = (const float*)d_in[5];
    const float* Wk_s = (const float*)d_in[6];
    const float* bk_s = (const float*)d_in[7];
    const float* Wv   = (const float*)d_in[8];
    float* o = (float*)d_out;

    u16* qh  = (u16*)d_ws;                 // 65536*128
    u16* ql  = qh + 8388608;               // 65536*64
    u16* kh  = ql + 4194304;               // 65536*128
    u16* kl  = kh + 8388608;               // 65536*64
    u16* vth = kl + 4194304;               // 64*64*1024
    float* po = (float*)(vth + 4194304);   // 2*65536*64 f32
    float2* pml = (float2*)(po + 8388608); // 2*65536 float2
    u16* gmh = (u16*)(pml + 131072);       // 4096 each
    u16* gml = gmh + 4096;
    u16* mvh = gml + 4096;
    u16* mvl = mvh + 4096;

    g_kernel<<<8, 256, 0, stream>>>(Wq, Wk, Wv, gmh, gml, mvh, mvl);
    prep_kernel<<<2048, 256, 0, stream>>>(vectors, scalars, Wq_s, bq_s,
                                          Wk_s, bk_s, gmh, gml, mvh, mvl,
                                          qh, ql, kh, kl, vth);
    attn_kernel<<<1024, 256, 0, stream>>>(qh, ql, kh, kl, vth, po, pml);
    merge_kernel<<<1024, 256, 0, stream>>>(po, pml, o);
}